// Round 20
// baseline (766.575 us; speedup 1.0000x reference)
//
#include <hip/hip_runtime.h>

#define UNR _Pragma("unroll")

typedef __attribute__((ext_vector_type(8))) short short8v;
typedef __attribute__((ext_vector_type(4))) float f32x4;

__device__ __forceinline__ ushort f2bf(float f) {
    union { float f; unsigned u; } x; x.f = f;
    unsigned r = (x.u + 0x7fffu + ((x.u >> 16) & 1u)) >> 16;
    return (ushort)r;
}
__device__ __forceinline__ float bf2f(ushort u) {
    union { unsigned u; float f; } x; x.u = ((unsigned)u) << 16;
    return x.f;
}

// async global->LDS, 16B per lane, dest = wave-uniform base + lane*16
__device__ __forceinline__ void gll16(const ushort* gp, ushort* lp) {
    __builtin_amdgcn_global_load_lds(
        (const __attribute__((address_space(1))) unsigned int*)(const void*)gp,
        (__attribute__((address_space(3))) unsigned int*)(void*)lp, 16, 0, 0);
}

// ---------------------------------------------------------------------------
// conv1 only (CI4): contiguous B, register-pipelined.
// ---------------------------------------------------------------------------
template<int Wp,int Hp,int OW,int OH,int WpN,int HpN,int PADN,int CN,int WAVES>
__global__ __launch_bounds__(WAVES*64)
void convc1(const ushort* __restrict__ Xp, const ushort* __restrict__ Wb,
            const float* __restrict__ bias, ushort* __restrict__ Yp)
{
    constexpr int CIN = 4, STRIDE = 2, NSTEP = 7;
    constexpr int POW = OW/2, POH = OH/2;
    constexpr int NTOT = 16*POW*POH*4;

    const int lane = (int)threadIdx.x & 63;
    const int wave = (int)threadIdx.x >> 6;
    const int n0   = (blockIdx.y*WAVES + wave) * 64;
    const int lm   = lane & 15;
    const int lk   = lane >> 4;

    int ns[4];
    unsigned boff[4];
    UNR for (int nf=0; nf<4; ++nf) {
        int n = n0 + nf*16 + lm;
        if (n > NTOT-1) n = NTOT-1;
        ns[nf] = n;
        int q = n & 3, pp = n >> 2;
        int px = pp % POW; int t = pp / POW;
        int py = t % POH;  int b = t / POH;
        int oy = 2*py + (q>>1), ox = 2*px + (q&1);
        boff[nf] = ((unsigned)(b*Hp + oy*STRIDE)*Wp + (unsigned)(ox*STRIDE))*CIN
                 + 8u*lk;
    }

    f32x4 acc[4][4];
    UNR for (int i=0;i<4;++i) UNR for (int j=0;j<4;++j) acc[i][j] = f32x4{0.f,0.f,0.f,0.f};

    auto ldfr = [&](int s, short8v (&a)[4], short8v (&bf)[4]) {
        const unsigned xoff = (unsigned)(s*Wp*CIN);
        UNR for (int mf=0; mf<4; ++mf)
            a[mf] = *(const short8v*)(Wb + (unsigned)((s*4 + mf)<<9) + (unsigned)lane*8);
        UNR for (int nf=0; nf<4; ++nf)
            bf[nf] = *(const short8v*)(Xp + boff[nf] + xoff);
    };
    auto dm = [&](short8v (&a)[4], short8v (&bf)[4]) {
        UNR for (int mf=0; mf<4; ++mf)
            UNR for (int nf=0; nf<4; ++nf)
                acc[mf][nf] = __builtin_amdgcn_mfma_f32_16x16x32_bf16(
                                  a[mf], bf[nf], acc[mf][nf], 0, 0, 0);
    };

    short8v aA[4], bA[4], aB[4], bB[4];
    ldfr(0, aA, bA);
    for (int sb = 0; sb < NSTEP; sb += 2) {
        if (sb+1 < NSTEP) ldfr(sb+1, aB, bB);
        dm(aA, bA);
        if (sb+2 < NSTEP) ldfr(sb+2, aA, bA);
        if (sb+1 < NSTEP) dm(aB, bB);
    }

    UNR for (int mf=0; mf<4; ++mf) {
        const int co = mf*16 + 4*lk;
        f32x4 bi = *(const f32x4*)(bias + co);
        UNR for (int nf=0; nf<4; ++nf) {
            f32x4 v = acc[mf][nf];
            UNR for (int r=0;r<4;++r) {
                float t2 = v[r] + bi[r];
                t2 = fmaxf(t2, __shfl_xor(t2, 1, 64));
                t2 = fmaxf(t2, __shfl_xor(t2, 2, 64));
                v[r] = t2;
            }
            if ((lane & 3) == 0 && (n0 + nf*16 + lm) < NTOT) {
                int pp = ns[nf] >> 2;
                int px = pp % POW; int t2 = pp / POW;
                int py = t2 % POH; int b = t2 / POH;
                unsigned off = ((unsigned)(b*HpN + py + PADN)*WpN
                                + (unsigned)(px + PADN))*CN + co;
                ushort4 s; s.x=f2bf(v[0]); s.y=f2bf(v[1]); s.z=f2bf(v[2]); s.w=f2bf(v[3]);
                *(ushort4*)(Yp + off) = s;
            }
        }
    }
}

// ---------------------------------------------------------------------------
// Unified MFMA conv, block-cooperative LDS staging (r13 2-buffer structure).
// LINX>0: 1-D grid, XCD-pinned decomposition (bijective when LINX*LINY%8==0).
// ---------------------------------------------------------------------------
template<int CIN,int K,int STRIDE,int Wp,int Hp,int OW,int OH,int COUT,
         bool POOL,int WpN,int HpN,int PADN,int CN,int MT,int NT,int SPLITS,
         int LINX=0,int LINY=0>
__global__ __launch_bounds__(256)
void convt(const ushort* __restrict__ Xp, const ushort* __restrict__ Wb,
           const float* __restrict__ bias, ushort* __restrict__ Yp,
           float* __restrict__ part)
{
    static_assert(MT*NT == 4, "4 waves");
    constexpr int POW = OW/2, POH = OH/2;
    constexpr int NTOT = POOL ? 16*POW*POH*4 : 16*OW*OH;
    constexpr int NCH = CIN/32, NSTEP = K*K*NCH;
    constexpr int SPS = NSTEP/SPLITS;
    constexpr int CA = MT*4, CB = NT*4, CPW = MT + NT;

    int bx, by;
    if constexpr (LINX > 0) {
        constexpr int CHUNK = LINX*LINY/8;
        int bid = (int)blockIdx.x;
        int p = (bid & 7)*CHUNK + (bid >> 3);
        bx = p % LINX; by = p / LINX;
    } else {
        bx = (int)blockIdx.x; by = (int)blockIdx.y;
    }

    const int t    = (int)threadIdx.x;
    const int lane = t & 63;
    const int w    = t >> 6;
    const int mr   = w / NT, nc = w % NT;
    const int cy0  = bx * MT;
    const int n0b  = by * (NT*64);
    const int nw0  = n0b + nc*64;
    const int lm   = lane & 15, lk = lane >> 4;
    const int s0   = blockIdx.z * SPS, sE = s0 + SPS;

    __shared__ __align__(1024) ushort Ab[2][CA*512];
    __shared__ __align__(1024) ushort Bb[2][CB*512];

    auto nmap = [&](int n, int& b, int& oy, int& ox) {
        if (n > NTOT-1) n = NTOT-1;
        if constexpr (POOL) {
            int q = n & 3, pp = n >> 2;
            int px = pp % POW; int tt = pp / POW;
            int py = tt % POH;  b = tt / POH;
            oy = 2*py + (q>>1); ox = 2*px + (q&1);
        } else {
            ox = n % OW; int tt = n / OW; oy = tt % OH; b = tt / OH;
        }
    };

    int ns[4];
    UNR for (int nf=0; nf<4; ++nf) {
        int n = nw0 + nf*16 + lm;
        if (n > NTOT-1) n = NTOT-1;
        ns[nf] = n;
    }

    unsigned bsrc[CPW];
    UNR for (int j=0; j<CPW; ++j) {
        int q = w*CPW + j;
        if (q >= CA) {
            int bq = q - CA;
            int n = n0b + bq*16 + (lane >> 2);
            int b, oy, ox; nmap(n, b, oy, ox);
            bsrc[j] = ((unsigned)(b*Hp + oy*STRIDE)*Wp + (unsigned)(ox*STRIDE))*CIN
                    + (unsigned)(lane & 3)*8u;
        } else bsrc[j] = 0;
    }

    auto xoffs = [&](int s) -> unsigned {
        int c0  = (s % NCH)*32;
        int kxy = s / NCH;
        int kx  = kxy % K, ky = kxy / K;
        return (unsigned)((ky*Wp + kx)*CIN + c0);
    };
    auto stage = [&](int s, int buf) {
        const unsigned xoff = xoffs(s);
        UNR for (int j=0; j<CPW; ++j) {
            int q = w*CPW + j;
            if (q < CA) {
                const ushort* src = Wb
                    + ((size_t)(((cy0 + (q>>2))*NSTEP + s)*4 + (q&3)) << 9)
                    + (unsigned)lane*8;
                gll16(src, &Ab[buf][(unsigned)q*512u + (unsigned)lane*8u]);
            } else {
                gll16(Xp + bsrc[j] + xoff,
                      &Bb[buf][(unsigned)(q-CA)*512u + (unsigned)lane*8u]);
            }
        }
    };

    f32x4 acc[4][4];
    UNR for (int i=0;i<4;++i) UNR for (int j=0;j<4;++j) acc[i][j] = f32x4{0.f,0.f,0.f,0.f};

    auto compute = [&](int buf) {
        short8v a[4], bf[4];
        UNR for (int mf=0; mf<4; ++mf)
            a[mf] = *(const short8v*)&Ab[buf][(unsigned)((mr*4+mf)*64 + lane)*8u];
        UNR for (int nf=0; nf<4; ++nf)
            bf[nf] = *(const short8v*)&Bb[buf][(unsigned)((nc*64 + nf*16 + lm)*4 + lk)*8u];
        __builtin_amdgcn_s_setprio(1);
        UNR for (int mf=0; mf<4; ++mf)
            UNR for (int nf=0; nf<4; ++nf)
                acc[mf][nf] = __builtin_amdgcn_mfma_f32_16x16x32_bf16(
                                  a[mf], bf[nf], acc[mf][nf], 0, 0, 0);
        __builtin_amdgcn_s_setprio(0);
    };

    stage(s0, 0);
    __syncthreads();
    int buf = 0;
    for (int s = s0; s < sE; ++s) {
        if (s+1 < sE) stage(s+1, buf^1);
        compute(buf);
        __syncthreads();
        buf ^= 1;
    }

    UNR for (int mf=0; mf<4; ++mf) {
        const int co = (cy0 + mr)*64 + mf*16 + 4*lk;
        if constexpr (SPLITS > 1) {
            UNR for (int nf=0; nf<4; ++nf) {
                if ((nw0 + nf*16 + lm) < NTOT)
                    *(f32x4*)(part + ((size_t)blockIdx.z*NTOT + ns[nf])*COUT + co)
                        = acc[mf][nf];
            }
        } else {
            f32x4 bi = *(const f32x4*)(bias + co);
            UNR for (int nf=0; nf<4; ++nf) {
                f32x4 v = acc[mf][nf];
                UNR for (int r=0;r<4;++r) v[r] += bi[r];
                if constexpr (POOL) {
                    UNR for (int r=0;r<4;++r) {
                        float tt = v[r];
                        tt = fmaxf(tt, __shfl_xor(tt, 1, 64));
                        tt = fmaxf(tt, __shfl_xor(tt, 2, 64));
                        v[r] = tt;
                    }
                    if ((lane & 3) == 0 && (nw0 + nf*16 + lm) < NTOT) {
                        int pp = ns[nf] >> 2;
                        int px = pp % POW; int t2 = pp / POW;
                        int py = t2 % POH; int b = t2 / POH;
                        unsigned off = ((unsigned)(b*HpN + py + PADN)*WpN
                                        + (unsigned)(px + PADN))*CN + co;
                        ushort4 s2; s2.x=f2bf(v[0]); s2.y=f2bf(v[1]); s2.z=f2bf(v[2]); s2.w=f2bf(v[3]);
                        *(ushort4*)(Yp + off) = s2;
                    }
                } else {
                    if ((nw0 + nf*16 + lm) < NTOT) {
                        int n = ns[nf];
                        int ox = n % OW; int t2 = n / OW; int oy = t2 % OH; int b = t2 / OH;
                        unsigned off = ((unsigned)(b*HpN + oy)*WpN + (unsigned)ox)*CN + co;
                        ushort4 s2; s2.x=f2bf(v[0]); s2.y=f2bf(v[1]); s2.z=f2bf(v[2]); s2.w=f2bf(v[3]);
                        *(ushort4*)(Yp + off) = s2;
                    }
                }
            }
        }
    }
}

// part[ks][n][co] -> +bias -> bf16 NHWC (no pad); 4 co per thread (float4)
template<int COUT,int OW,int OH,int WpN,int HpN,int CN,int SPLITS>
__global__ void kreduce(const float* __restrict__ part, const float* __restrict__ bias,
                        ushort* __restrict__ Yp) {
    constexpr int NTOT = 16*OW*OH;
    constexpr int C4 = COUT/4;
    int idx = blockIdx.x*256 + (int)threadIdx.x;
    if (idx >= NTOT*C4) return;
    int c4 = (idx % C4)*4; int n = idx / C4;
    f32x4 sum = *(const f32x4*)(part + ((size_t)n)*COUT + c4);
    UNR for (int ks=1; ks<SPLITS; ++ks) {
        f32x4 p = *(const f32x4*)(part + ((size_t)ks*NTOT + n)*COUT + c4);
        UNR for (int r=0;r<4;++r) sum[r] += p[r];
    }
    f32x4 bi = *(const f32x4*)(bias + c4);
    int ox = n % OW; int t = n / OW; int oy = t % OH; int b = t / OH;
    ushort4 s;
    s.x = f2bf(sum[0]+bi[0]); s.y = f2bf(sum[1]+bi[1]);
    s.z = f2bf(sum[2]+bi[2]); s.w = f2bf(sum[3]+bi[3]);
    *(ushort4*)(Yp + ((unsigned)(b*HpN + oy)*WpN + (unsigned)ox)*CN + c4) = s;
}

// ---------------------------------------------------------------------------
// x (16,3,448,448) f32 -> full padded X1 bf16 [b][y][x][ci4] (zeros in halo)
// ---------------------------------------------------------------------------
__global__ void x1build(const float* __restrict__ x, ushort* __restrict__ X1) {
    int idx = blockIdx.x*256 + (int)threadIdx.x;      // 16*456*456 = 3,326,976
    int xx = idx % 456; int t = idx/456; int y = t % 456; int b = t/456;
    ushort4 s; s.x = 0; s.y = 0; s.z = 0; s.w = 0;
    if (xx >= 3 && xx < 451 && y >= 3 && y < 451) {
        const float* px = x + ((size_t)b*3*448 + (y-3))*448 + (xx-3);
        s.x = f2bf(px[0]); s.y = f2bf(px[200704]); s.z = f2bf(px[401408]);
    }
    *(ushort4*)(X1 + ((unsigned)(b*456 + y)*456 + (unsigned)xx)*4) = s;
}

// zero X3's pad ring only (rows/cols 0 and 113)
__global__ void x3ring(ushort* __restrict__ X3) {
    int idx = blockIdx.x*256 + (int)threadIdx.x;
    if (idx >= 462848) return;
    int b = idx / 28928; int j = idx % 28928;
    unsigned off;
    if (j < 14592) {
        int r = j / 7296; int rem = j % 7296;
        int y = r ? 113 : 0;
        off = ((unsigned)(b*114 + y)*114)*64u + (unsigned)rem;
    } else {
        int j2 = j - 14592;
        int y = 1 + j2/128;
        int rem = j2 % 128;
        int xx = (rem >> 6) ? 113 : 0;
        off = (((unsigned)(b*114 + y)*114) + (unsigned)xx)*64u + (unsigned)(rem & 63);
    }
    X3[off] = 0;
}

// w1 (64,3,7,7) -> fragment order
__global__ void wcvt1(const float* __restrict__ w, ushort* __restrict__ o) {
    int idx = blockIdx.x*256 + (int)threadIdx.x;      // 14336
    if (idx >= 14336) return;
    int e = idx & 7; int t = idx >> 3;
    int lane = t & 63; t >>= 6;
    int mf = t & 3; int s = t >> 2;
    int co = mf*16 + (lane & 15);
    int cc = (lane >> 4)*8 + e;
    int kx = cc >> 2, ci = cc & 3;
    float v = 0.f;
    if (kx < 7 && ci < 3) v = w[(((size_t)co*3 + ci)*7 + s)*7 + kx];
    o[idx] = f2bf(v);
}

// generic OIHW -> fragment order [cy][s][mf][lane][8e]
template<int CIN,int K,int COUT>
__global__ void wcvt(const float* __restrict__ w, ushort* __restrict__ o) {
    constexpr int NCH = CIN/32, NSTEP = K*K*NCH;
    int idx = blockIdx.x*256 + (int)threadIdx.x;
    if (idx >= COUT*K*K*CIN) return;
    int e = idx & 7; int t = idx >> 3;
    int lane = t & 63; t >>= 6;
    int mf = t & 3; t >>= 2;
    int s = t % NSTEP; int cy = t / NSTEP;
    int co = cy*64 + mf*16 + (lane & 15);
    int kxy = s / NCH, ch = s % NCH;
    int ci = ch*32 + (lane >> 4)*8 + e;
    int ky = kxy / K, kx = kxy % K;
    o[idx] = f2bf(w[(((size_t)co*CIN + ci)*K + ky)*K + kx]);
}

// ---------------------------------------------------------------------------
// maxpool k=5 s=4: XU3 bf16 NHWC (16,10,10,1024) -> pp f32 [b*1024+c][4]
// ---------------------------------------------------------------------------
__global__ void pool54_k(const ushort* __restrict__ in, float* __restrict__ out) {
    int idx = blockIdx.x*256 + (int)threadIdx.x;      // 65536
    int c = idx & 1023; int t = idx >> 10; int q = t & 3; int b = t >> 2;
    int i = q >> 1, j = q & 1;
    float m = -1e30f;
    UNR for (int r=0;r<5;++r)
        UNR for (int cc=0;cc<5;++cc)
            m = fmaxf(m, bf2f(in[(((unsigned)(b*10 + i*4+r))*10 + (unsigned)(j*4+cc))*1024 + c]));
    out[((size_t)(b*1024 + c))*4 + q] = m;
}

// ---------------------------------------------------------------------------
__device__ __forceinline__ void bigrid(int k, int& lo, float& f) {
    float c = ((float)k + 0.5f) * (2.0f/7.0f) - 0.5f;
    c = fminf(fmaxf(c, 0.f), 1.f);
    float fl = floorf(c);
    lo = (int)fl;
    f = c - fl;
}

// bilinear+pad+im2col to padded-k bf16:  Pb[hw][b][c][k'16], k'>=9 -> 0
__global__ void buildPb(const float* __restrict__ pp, ushort* __restrict__ Pb) {
    int idx = blockIdx.x*256 + (int)threadIdx.x;   // 12,845,056 exactly
    int k = idx & 15;
    int c = (idx >> 4) & 1023;
    int r = idx >> 14;
    int b = r & 15; int hw = r >> 4;
    float val = 0.f;
    if (k < 9) {
        int i = k/3, j = k%3;
        int h = hw/7, w2 = hw%7;
        int rr = h + i - 1, cc = w2 + j - 1;
        if (rr>=0 && rr<7 && cc>=0 && cc<7) {
            int rlo; float rf; bigrid(rr, rlo, rf);
            int clo; float cf; bigrid(cc, clo, cf);
            int rhi = min(rlo+1,1), chi = min(clo+1,1);
            const float* qq = pp + ((size_t)(b*1024 + c))*4;
            float v00=qq[rlo*2+clo], v01=qq[rlo*2+chi], v10=qq[rhi*2+clo], v11=qq[rhi*2+chi];
            float top = v00*(1.f-cf) + v01*cf;
            float bot = v10*(1.f-cf) + v11*cf;
            val = top*(1.f-rf) + bot*rf;
        }
    }
    Pb[idx] = f2bf(val);
}

// ---------------------------------------------------------------------------
// Fused local-conv, barrier-free wave-partitioned staging (r11 version).
// ---------------------------------------------------------------------------
__global__ __launch_bounds__(256)
void lconv_fused(const float* __restrict__ lcw, const ushort* __restrict__ Pb,
                 float* __restrict__ part) {
    const int bid = (int)blockIdx.x;      // 0..783
    const int xcd = bid & 7;
    const int i   = bid >> 3;             // 0..97
    const int hw  = i % 49;
    const int ks  = xcd + 8*(i/49);       // 0..15, pinned to xcd
    const int t   = (int)threadIdx.x;
    const int lane = t & 63, w = t >> 6;
    const int lm = lane & 15, lk = lane >> 4;
    const int c0 = ks*64;

    __shared__ ushort A[2][8192];         // 2 x 16KB

    auto ldreg = [&](int cc, float (&w9)[2][9]) {
        const int cb = c0 + cc*2;
        UNR for (int cl=0; cl<2; ++cl) {
            const float* src = lcw + ((size_t)(cb+cl)*256 + (unsigned)(w*64+lane))*441
                             + hw*9;
            __builtin_memcpy(w9[cl], src, 36);
        }
    };
    auto wrlds = [&](int buf, float (&w9)[2][9]) {
        UNR for (int cl=0; cl<2; ++cl) {
            int rem = cl*256 + w*64 + lane;
            ushort u[16];
            UNR for (int k=0;k<8;++k) u[k]=f2bf(w9[cl][k]);
            u[8]=f2bf(w9[cl][8]);
            UNR for (int k=9;k<16;++k) u[k]=0;
            *(short8v*)&A[buf][(unsigned)rem*8u] = *(short8v*)&u[0];
            *(short8v*)&A[buf][4096u + (unsigned)rem*8u] = *(short8v*)&u[8];
        }
    };

    f32x4 acc[4];
    UNR for (int q=0;q<4;++q) acc[q] = f32x4{0.f,0.f,0.f,0.f};

    const ushort* Bb = Pb + (size_t)(hw*16 + lm)*16384 + ks*1024 + lk*8;
    const int arow = (lk&1)*512 + (lk>>1)*256 + w*64 + lm;

    auto mmac = [&](int buf, int cc) {
        short8v bv = *(const short8v*)(Bb + cc*32);
        UNR for (int mf = 0; mf < 4; ++mf) {
            short8v av = *(const short8v*)&A[buf][(unsigned)(arow + mf*16)*8u];
            acc[mf] = __builtin_amdgcn_mfma_f32_16x16x32_bf16(av, bv, acc[mf], 0,0,0);
        }
    };

    float wA[2][9], wB[2][9];
    ldreg(0, wA);
    wrlds(0, wA);
    ldreg(1, wB);
    for (int cc = 0; cc < 32; cc += 2) {
        mmac(0, cc);
        wrlds(1, wB);
        if (cc+2 < 32) ldreg(cc+2, wA);
        mmac(1, cc+1);
        if (cc+2 < 32) {
            wrlds(0, wA);
            if (cc+3 < 32) ldreg(cc+3, wB);
        }
    }

    UNR for (int mf=0; mf<4; ++mf)
        UNR for (int r=0;r<4;++r) {
            int o = w*64 + mf*16 + 4*lk + r;
            part[(((size_t)ks*49 + hw)*256 + o)*16 + lm] = acc[mf][r];
        }
}

// part [ks][hw][o][b] -> yact[b][o*49+hw]; 4 b per thread (float4 reads)
__global__ void lreduce2(const float* __restrict__ part, const float* __restrict__ lcb,
                         float* __restrict__ yact) {
    int idx = blockIdx.x*256 + (int)threadIdx.x;  // 50176 exactly
    int b4 = (idx & 3)*4; int o = (idx >> 2) & 255; int hw = idx >> 10;
    f32x4 sum = *(const f32x4*)(part + (((size_t)hw)*256 + o)*16 + b4);
    UNR for (int ks=1; ks<16; ++ks) {
        f32x4 p = *(const f32x4*)(part + (((size_t)ks*49 + hw)*256 + o)*16 + b4);
        UNR for (int r=0;r<4;++r) sum[r] += p[r];
    }
    float bias = lcb[o*49 + hw];
    UNR for (int r=0;r<4;++r) {
        float s = sum[r] + bias;
        yact[(b4+r)*12544 + o*49 + hw] = (s > 0.f) ? s : 0.1f*s;
    }
}

// ---------------------------------------------------------------------------
// FC: float4 weight stream (16B/lane), r19 version.
// ---------------------------------------------------------------------------
__global__ __launch_bounds__(256)
void fc_k(const float* __restrict__ act, const float* __restrict__ fw,
          const float* __restrict__ fb, float* __restrict__ out) {
    __shared__ float red[4][4][16];
    const int t = (int)threadIdx.x;
    const int o0 = blockIdx.x*4;
    float acc[4][16];
    UNR for (int oo=0;oo<4;++oo) UNR for (int b=0;b<16;++b) acc[oo][b]=0.f;

    const int kt = t*4;
    for (int k0 = 0; k0 < 12288; k0 += 1024) {
        int k = k0 + kt;
        f32x4 wv[4];
        UNR for (int oo=0;oo<4;++oo) {
            int o = o0+oo;
            wv[oo] = (o < 4949) ? *(const f32x4*)(fw + (size_t)o*12544 + k)
                                : f32x4{0.f,0.f,0.f,0.f};
        }
        UNR for (int b=0;b<16;++b) {
            f32x4 av = *(const f32x4*)(act + b*12544 + k);
            UNR for (int oo=0;oo<4;++oo) {
                acc[oo][b] = fmaf(wv[oo][0], av[0], acc[oo][b]);
                acc[oo][b] = fmaf(wv[oo][1], av[1], acc[oo][b]);
                acc[oo][b] = fmaf(wv[oo][2], av[2], acc[oo][b]);
                acc[oo][b] = fmaf(wv[oo][3], av[3], acc[oo][b]);
            }
        }
    }
    if (t < 64) {                       // tail k = 12288..12543
        int k = 12288 + kt;
        f32x4 wv[4];
        UNR for (int oo=0;oo<4;++oo) {
            int o = o0+oo;
            wv[oo] = (o < 4949) ? *(const f32x4*)(fw + (size_t)o*12544 + k)
                                : f32x4{0.f,0.f,0.f,0.f};
        }
        UNR for (int b=0;b<16;++b) {
            f32x4 av = *(const f32x4*)(act + b*12544 + k);
            UNR for (int oo=0;oo<4;++oo) {
                acc[oo][b] = fmaf(wv[oo][0], av[0], acc[oo][b]);
                acc[oo][b] = fmaf(wv[oo][1], av[1], acc[oo][b]);
                acc[oo][b] = fmaf(wv[oo][2], av[2], acc[oo][b]);
                acc[oo][b] = fmaf(wv[oo][3], av[3], acc[oo][b]);
            }
        }
    }

    UNR for (int oo=0;oo<4;++oo)
        UNR for (int b=0;b<16;++b) {
            float v = acc[oo][b];
            UNR for (int off=32; off; off>>=1) v += __shfl_xor(v, off, 64);
            acc[oo][b] = v;
        }
    const int wave = t>>6, lane = t&63;
    if (lane == 0)
        UNR for (int oo=0;oo<4;++oo)
            UNR for (int b=0;b<16;++b) red[wave][oo][b] = acc[oo][b];
    __syncthreads();
    if (t < 64) {
        int oo = t>>4, b = t&15;
        float v = red[0][oo][b]+red[1][oo][b]+red[2][oo][b]+red[3][oo][b];
        int o = o0+oo;
        if (o < 4949) out[b*4949 + o] = v + fb[o];
    }
}

// ---------------------------------------------------------------------------
extern "C" void kernel_launch(void* const* d_in, const int* in_sizes, int n_in,
                              void* d_out, int out_size, void* d_ws, size_t ws_size,
                              hipStream_t stream) {
    const float* x   = (const float*)d_in[0];
    const float* w1  = (const float*)d_in[1];
    const float* b1  = (const float*)d_in[2];
    const float* w3  = (const float*)d_in[3];
    const float* b3  = (const float*)d_in[4];
    const float* w4  = (const float*)d_in[5];
    const float* b4  = (const float*)d_in[6];
    const float* w7  = (const float*)d_in[7];
    const float* b7  = (const float*)d_in[8];
    const float* w8  = (const float*)d_in[9];
    const float* b8  = (const float*)d_in[10];
    const float* wu  = (const float*)d_in[11];
    const float* bu  = (const float*)d_in[12];
    const float* lcw = (const float*)d_in[13];
    const float* lcb = (const float*)d_in[14];
    const float* fw  = (const float*)d_in[15];
    const float* fb  = (const float*)d_in[16];
    float* out = (float*)d_out;

    // --- workspace carve (bytes, 256-aligned) ---
    char* base = (char*)d_ws;
    auto alloc = [&](size_t bytes) { char* p = base; base += (bytes + 255) & ~(size_t)255; return p; };
    ushort* X1  = (ushort*)alloc(16u*456*456*4*2);
    ushort* X3  = (ushort*)alloc(16u*114*114*64*2);
    ushort* X4  = (ushort*)alloc(16u*56*56*192*2);
    ushort* X7  = (ushort*)alloc(16u*27*27*256*2);   // later reused as yact
    ushort* X8  = (ushort*)alloc(16u*13*13*512*2);
    ushort* XU1 = (ushort*)alloc(16u*12*12*1024*2);
    ushort* XU2 = (ushort*)alloc(16u*11*11*1024*2);
    ushort* XU3 = (ushort*)alloc(16u*10*10*1024*2);
    ushort* W1b = (ushort*)alloc(64u*224*2);
    ushort* W3b = (ushort*)alloc(192u*576*2);
    ushort* W4b = (ushort*)alloc(256u*1728*2);
    ushort* W7b = (ushort*)alloc(512u*1024*2);
    ushort* W8b = (ushort*)alloc(1024u*2048*2);
    ushort* WUb = (ushort*)alloc(1024u*4096*2);
    float*  pp  = (float*)alloc(16u*1024*4*4);
    ushort* Pb  = (ushort*)alloc((size_t)49*16*16384*2);     // 25.7 MB
    float*  part = (float*)alloc((size_t)16*49*256*16*4);    // 12.8 MB
    float*  partK = (float*)alloc((size_t)8*2304*1024*4);    // 75.5 MB (K-split x8)
    float*  yact = (float*)X7;                               // X7 dead by then

    // --- prep ---
    x1build<<<12996, 256, 0, stream>>>(x, X1);
    x3ring<<<1808, 256, 0, stream>>>(X3);
    wcvt1<<<56, 256, 0, stream>>>(w1, W1b);
    wcvt<64,3,192><<<432, 256, 0, stream>>>(w3, W3b);
    wcvt<192,3,256><<<1728, 256, 0, stream>>>(w4, W4b);
    wcvt<256,2,512><<<2048, 256, 0, stream>>>(w7, W7b);
    wcvt<512,2,1024><<<8192, 256, 0, stream>>>(w8, W8b);
    wcvt<1024,2,1024><<<16384, 256, 0, stream>>>(wu, WUb);

    // --- conv chain ---
    convc1<456,456,224,224,114,114,1,64, 4>
        <<<dim3(1,3136), 256, 0, stream>>>(X1, W1b, b1, X3);
    convt<64,3,1,114,114,112,112,192, true,56,56,0,192, 1,4,1, 3,784>
        <<<2352, 256, 0, stream>>>(X3, W3b, b3, X4, nullptr);
    convt<192,3,1,56,56,54,54,256, true,27,27,0,256, 2,2,1>
        <<<dim3(2,365,1), 256, 0, stream>>>(X4, W4b, b4, X7, nullptr);
    convt<256,2,1,27,27,26,26,512, true,13,13,0,512, 2,2,1>
        <<<dim3(4,85,1), 256, 0, stream>>>(X7, W7b, b7, X8, nullptr);
    // K-split x8 (SPS: conv8=8, convu=16) for ~4.5 blocks/CU occupancy
    convt<512,2,1,13,13,12,12,1024, false,12,12,0,1024, 2,2,8>
        <<<dim3(8,18,8), 256, 0, stream>>>(X8, W8b, nullptr, nullptr, partK);
    kreduce<1024,12,12,12,12,1024,8><<<2304, 256, 0, stream>>>(partK, b8, XU1);
    convt<1024,2,1,12,12,11,11,1024, false,11,11,0,1024, 2,2,8>
        <<<dim3(8,16,8), 256, 0, stream>>>(XU1, WUb, nullptr, nullptr, partK);
    kreduce<1024,11,11,11,11,1024,8><<<1936, 256, 0, stream>>>(partK, bu, XU2);
    convt<1024,2,1,11,11,10,10,1024, false,10,10,0,1024, 2,2,8>
        <<<dim3(8,13,8), 256, 0, stream>>>(XU2, WUb, nullptr, nullptr, partK);
    kreduce<1024,10,10,10,10,1024,8><<<1600, 256, 0, stream>>>(partK, bu, XU3);

    // --- head ---
    pool54_k<<<256, 256, 0, stream>>>(XU3, pp);
    buildPb<<<50176, 256, 0, stream>>>(pp, Pb);
    lconv_fused<<<784, 256, 0, stream>>>(lcw, Pb, part);
    lreduce2<<<196, 256, 0, stream>>>(part, lcb, yact);
    fc_k<<<1238, 256, 0, stream>>>(yact, fw, fb, out);
}

// Round 21
// 712.499 us; speedup vs baseline: 1.0759x; 1.0759x over previous
//
#include <hip/hip_runtime.h>

#define UNR _Pragma("unroll")

typedef __attribute__((ext_vector_type(8))) short short8v;
typedef __attribute__((ext_vector_type(4))) float f32x4;

__device__ __forceinline__ ushort f2bf(float f) {
    union { float f; unsigned u; } x; x.f = f;
    unsigned r = (x.u + 0x7fffu + ((x.u >> 16) & 1u)) >> 16;
    return (ushort)r;
}
__device__ __forceinline__ float bf2f(ushort u) {
    union { unsigned u; float f; } x; x.u = ((unsigned)u) << 16;
    return x.f;
}

// async global->LDS, 16B per lane, dest = wave-uniform base + lane*16
__device__ __forceinline__ void gll16(const ushort* gp, ushort* lp) {
    __builtin_amdgcn_global_load_lds(
        (const __attribute__((address_space(1))) unsigned int*)(const void*)gp,
        (__attribute__((address_space(3))) unsigned int*)(void*)lp, 16, 0, 0);
}

// ---------------------------------------------------------------------------
// conv1 only (CI4): contiguous B, register-pipelined.
// ---------------------------------------------------------------------------
template<int Wp,int Hp,int OW,int OH,int WpN,int HpN,int PADN,int CN,int WAVES>
__global__ __launch_bounds__(WAVES*64)
void convc1(const ushort* __restrict__ Xp, const ushort* __restrict__ Wb,
            const float* __restrict__ bias, ushort* __restrict__ Yp)
{
    constexpr int CIN = 4, STRIDE = 2, NSTEP = 7;
    constexpr int POW = OW/2, POH = OH/2;
    constexpr int NTOT = 16*POW*POH*4;

    const int lane = (int)threadIdx.x & 63;
    const int wave = (int)threadIdx.x >> 6;
    const int n0   = (blockIdx.y*WAVES + wave) * 64;
    const int lm   = lane & 15;
    const int lk   = lane >> 4;

    int ns[4];
    unsigned boff[4];
    UNR for (int nf=0; nf<4; ++nf) {
        int n = n0 + nf*16 + lm;
        if (n > NTOT-1) n = NTOT-1;
        ns[nf] = n;
        int q = n & 3, pp = n >> 2;
        int px = pp % POW; int t = pp / POW;
        int py = t % POH;  int b = t / POH;
        int oy = 2*py + (q>>1), ox = 2*px + (q&1);
        boff[nf] = ((unsigned)(b*Hp + oy*STRIDE)*Wp + (unsigned)(ox*STRIDE))*CIN
                 + 8u*lk;
    }

    f32x4 acc[4][4];
    UNR for (int i=0;i<4;++i) UNR for (int j=0;j<4;++j) acc[i][j] = f32x4{0.f,0.f,0.f,0.f};

    auto ldfr = [&](int s, short8v (&a)[4], short8v (&bf)[4]) {
        const unsigned xoff = (unsigned)(s*Wp*CIN);
        UNR for (int mf=0; mf<4; ++mf)
            a[mf] = *(const short8v*)(Wb + (unsigned)((s*4 + mf)<<9) + (unsigned)lane*8);
        UNR for (int nf=0; nf<4; ++nf)
            bf[nf] = *(const short8v*)(Xp + boff[nf] + xoff);
    };
    auto dm = [&](short8v (&a)[4], short8v (&bf)[4]) {
        UNR for (int mf=0; mf<4; ++mf)
            UNR for (int nf=0; nf<4; ++nf)
                acc[mf][nf] = __builtin_amdgcn_mfma_f32_16x16x32_bf16(
                                  a[mf], bf[nf], acc[mf][nf], 0, 0, 0);
    };

    short8v aA[4], bA[4], aB[4], bB[4];
    ldfr(0, aA, bA);
    for (int sb = 0; sb < NSTEP; sb += 2) {
        if (sb+1 < NSTEP) ldfr(sb+1, aB, bB);
        dm(aA, bA);
        if (sb+2 < NSTEP) ldfr(sb+2, aA, bA);
        if (sb+1 < NSTEP) dm(aB, bB);
    }

    UNR for (int mf=0; mf<4; ++mf) {
        const int co = mf*16 + 4*lk;
        f32x4 bi = *(const f32x4*)(bias + co);
        UNR for (int nf=0; nf<4; ++nf) {
            f32x4 v = acc[mf][nf];
            UNR for (int r=0;r<4;++r) {
                float t2 = v[r] + bi[r];
                t2 = fmaxf(t2, __shfl_xor(t2, 1, 64));
                t2 = fmaxf(t2, __shfl_xor(t2, 2, 64));
                v[r] = t2;
            }
            if ((lane & 3) == 0 && (n0 + nf*16 + lm) < NTOT) {
                int pp = ns[nf] >> 2;
                int px = pp % POW; int t2 = pp / POW;
                int py = t2 % POH; int b = t2 / POH;
                unsigned off = ((unsigned)(b*HpN + py + PADN)*WpN
                                + (unsigned)(px + PADN))*CN + co;
                ushort4 s; s.x=f2bf(v[0]); s.y=f2bf(v[1]); s.z=f2bf(v[2]); s.w=f2bf(v[3]);
                *(ushort4*)(Yp + off) = s;
            }
        }
    }
}

// ---------------------------------------------------------------------------
// Unified MFMA conv, block-cooperative LDS staging (r13 2-buffer structure).
// LINX>0: 1-D grid, XCD-pinned decomposition (bijective when LINX*LINY%8==0).
// ---------------------------------------------------------------------------
template<int CIN,int K,int STRIDE,int Wp,int Hp,int OW,int OH,int COUT,
         bool POOL,int WpN,int HpN,int PADN,int CN,int MT,int NT,int SPLITS,
         int LINX=0,int LINY=0>
__global__ __launch_bounds__(256)
void convt(const ushort* __restrict__ Xp, const ushort* __restrict__ Wb,
           const float* __restrict__ bias, ushort* __restrict__ Yp,
           float* __restrict__ part)
{
    static_assert(MT*NT == 4, "4 waves");
    constexpr int POW = OW/2, POH = OH/2;
    constexpr int NTOT = POOL ? 16*POW*POH*4 : 16*OW*OH;
    constexpr int NCH = CIN/32, NSTEP = K*K*NCH;
    constexpr int SPS = NSTEP/SPLITS;
    constexpr int CA = MT*4, CB = NT*4, CPW = MT + NT;

    int bx, by;
    if constexpr (LINX > 0) {
        constexpr int CHUNK = LINX*LINY/8;
        int bid = (int)blockIdx.x;
        int p = (bid & 7)*CHUNK + (bid >> 3);
        bx = p % LINX; by = p / LINX;
    } else {
        bx = (int)blockIdx.x; by = (int)blockIdx.y;
    }

    const int t    = (int)threadIdx.x;
    const int lane = t & 63;
    const int w    = t >> 6;
    const int mr   = w / NT, nc = w % NT;
    const int cy0  = bx * MT;
    const int n0b  = by * (NT*64);
    const int nw0  = n0b + nc*64;
    const int lm   = lane & 15, lk = lane >> 4;
    const int s0   = blockIdx.z * SPS, sE = s0 + SPS;

    __shared__ __align__(1024) ushort Ab[2][CA*512];
    __shared__ __align__(1024) ushort Bb[2][CB*512];

    auto nmap = [&](int n, int& b, int& oy, int& ox) {
        if (n > NTOT-1) n = NTOT-1;
        if constexpr (POOL) {
            int q = n & 3, pp = n >> 2;
            int px = pp % POW; int tt = pp / POW;
            int py = tt % POH;  b = tt / POH;
            oy = 2*py + (q>>1); ox = 2*px + (q&1);
        } else {
            ox = n % OW; int tt = n / OW; oy = tt % OH; b = tt / OH;
        }
    };

    int ns[4];
    UNR for (int nf=0; nf<4; ++nf) {
        int n = nw0 + nf*16 + lm;
        if (n > NTOT-1) n = NTOT-1;
        ns[nf] = n;
    }

    unsigned bsrc[CPW];
    UNR for (int j=0; j<CPW; ++j) {
        int q = w*CPW + j;
        if (q >= CA) {
            int bq = q - CA;
            int n = n0b + bq*16 + (lane >> 2);
            int b, oy, ox; nmap(n, b, oy, ox);
            bsrc[j] = ((unsigned)(b*Hp + oy*STRIDE)*Wp + (unsigned)(ox*STRIDE))*CIN
                    + (unsigned)(lane & 3)*8u;
        } else bsrc[j] = 0;
    }

    auto xoffs = [&](int s) -> unsigned {
        int c0  = (s % NCH)*32;
        int kxy = s / NCH;
        int kx  = kxy % K, ky = kxy / K;
        return (unsigned)((ky*Wp + kx)*CIN + c0);
    };
    auto stage = [&](int s, int buf) {
        const unsigned xoff = xoffs(s);
        UNR for (int j=0; j<CPW; ++j) {
            int q = w*CPW + j;
            if (q < CA) {
                const ushort* src = Wb
                    + ((size_t)(((cy0 + (q>>2))*NSTEP + s)*4 + (q&3)) << 9)
                    + (unsigned)lane*8;
                gll16(src, &Ab[buf][(unsigned)q*512u + (unsigned)lane*8u]);
            } else {
                gll16(Xp + bsrc[j] + xoff,
                      &Bb[buf][(unsigned)(q-CA)*512u + (unsigned)lane*8u]);
            }
        }
    };

    f32x4 acc[4][4];
    UNR for (int i=0;i<4;++i) UNR for (int j=0;j<4;++j) acc[i][j] = f32x4{0.f,0.f,0.f,0.f};

    auto compute = [&](int buf) {
        short8v a[4], bf[4];
        UNR for (int mf=0; mf<4; ++mf)
            a[mf] = *(const short8v*)&Ab[buf][(unsigned)((mr*4+mf)*64 + lane)*8u];
        UNR for (int nf=0; nf<4; ++nf)
            bf[nf] = *(const short8v*)&Bb[buf][(unsigned)((nc*64 + nf*16 + lm)*4 + lk)*8u];
        __builtin_amdgcn_s_setprio(1);
        UNR for (int mf=0; mf<4; ++mf)
            UNR for (int nf=0; nf<4; ++nf)
                acc[mf][nf] = __builtin_amdgcn_mfma_f32_16x16x32_bf16(
                                  a[mf], bf[nf], acc[mf][nf], 0, 0, 0);
        __builtin_amdgcn_s_setprio(0);
    };

    stage(s0, 0);
    __syncthreads();
    int buf = 0;
    for (int s = s0; s < sE; ++s) {
        if (s+1 < sE) stage(s+1, buf^1);
        compute(buf);
        __syncthreads();
        buf ^= 1;
    }

    UNR for (int mf=0; mf<4; ++mf) {
        const int co = (cy0 + mr)*64 + mf*16 + 4*lk;
        if constexpr (SPLITS > 1) {
            UNR for (int nf=0; nf<4; ++nf) {
                if ((nw0 + nf*16 + lm) < NTOT)
                    *(f32x4*)(part + ((size_t)blockIdx.z*NTOT + ns[nf])*COUT + co)
                        = acc[mf][nf];
            }
        } else {
            f32x4 bi = *(const f32x4*)(bias + co);
            UNR for (int nf=0; nf<4; ++nf) {
                f32x4 v = acc[mf][nf];
                UNR for (int r=0;r<4;++r) v[r] += bi[r];
                if constexpr (POOL) {
                    UNR for (int r=0;r<4;++r) {
                        float tt = v[r];
                        tt = fmaxf(tt, __shfl_xor(tt, 1, 64));
                        tt = fmaxf(tt, __shfl_xor(tt, 2, 64));
                        v[r] = tt;
                    }
                    if ((lane & 3) == 0 && (nw0 + nf*16 + lm) < NTOT) {
                        int pp = ns[nf] >> 2;
                        int px = pp % POW; int t2 = pp / POW;
                        int py = t2 % POH; int b = t2 / POH;
                        unsigned off = ((unsigned)(b*HpN + py + PADN)*WpN
                                        + (unsigned)(px + PADN))*CN + co;
                        ushort4 s2; s2.x=f2bf(v[0]); s2.y=f2bf(v[1]); s2.z=f2bf(v[2]); s2.w=f2bf(v[3]);
                        *(ushort4*)(Yp + off) = s2;
                    }
                } else {
                    if ((nw0 + nf*16 + lm) < NTOT) {
                        int n = ns[nf];
                        int ox = n % OW; int t2 = n / OW; int oy = t2 % OH; int b = t2 / OH;
                        unsigned off = ((unsigned)(b*HpN + oy)*WpN + (unsigned)ox)*CN + co;
                        ushort4 s2; s2.x=f2bf(v[0]); s2.y=f2bf(v[1]); s2.z=f2bf(v[2]); s2.w=f2bf(v[3]);
                        *(ushort4*)(Yp + off) = s2;
                    }
                }
            }
        }
    }
}

// part[ks][n][co] -> +bias -> bf16 NHWC (no pad); 4 co per thread (float4)
template<int COUT,int OW,int OH,int WpN,int HpN,int CN,int SPLITS>
__global__ void kreduce(const float* __restrict__ part, const float* __restrict__ bias,
                        ushort* __restrict__ Yp) {
    constexpr int NTOT = 16*OW*OH;
    constexpr int C4 = COUT/4;
    int idx = blockIdx.x*256 + (int)threadIdx.x;
    if (idx >= NTOT*C4) return;
    int c4 = (idx % C4)*4; int n = idx / C4;
    f32x4 sum = *(const f32x4*)(part + ((size_t)n)*COUT + c4);
    UNR for (int ks=1; ks<SPLITS; ++ks) {
        f32x4 p = *(const f32x4*)(part + ((size_t)ks*NTOT + n)*COUT + c4);
        UNR for (int r=0;r<4;++r) sum[r] += p[r];
    }
    f32x4 bi = *(const f32x4*)(bias + c4);
    int ox = n % OW; int t = n / OW; int oy = t % OH; int b = t / OH;
    ushort4 s;
    s.x = f2bf(sum[0]+bi[0]); s.y = f2bf(sum[1]+bi[1]);
    s.z = f2bf(sum[2]+bi[2]); s.w = f2bf(sum[3]+bi[3]);
    *(ushort4*)(Yp + ((unsigned)(b*HpN + oy)*WpN + (unsigned)ox)*CN + c4) = s;
}

// ---------------------------------------------------------------------------
// x (16,3,448,448) f32 -> full padded X1 bf16 [b][y][x][ci4] (zeros in halo)
// ---------------------------------------------------------------------------
__global__ void x1build(const float* __restrict__ x, ushort* __restrict__ X1) {
    int idx = blockIdx.x*256 + (int)threadIdx.x;      // 16*456*456 = 3,326,976
    int xx = idx % 456; int t = idx/456; int y = t % 456; int b = t/456;
    ushort4 s; s.x = 0; s.y = 0; s.z = 0; s.w = 0;
    if (xx >= 3 && xx < 451 && y >= 3 && y < 451) {
        const float* px = x + ((size_t)b*3*448 + (y-3))*448 + (xx-3);
        s.x = f2bf(px[0]); s.y = f2bf(px[200704]); s.z = f2bf(px[401408]);
    }
    *(ushort4*)(X1 + ((unsigned)(b*456 + y)*456 + (unsigned)xx)*4) = s;
}

// zero X3's pad ring only (rows/cols 0 and 113)
__global__ void x3ring(ushort* __restrict__ X3) {
    int idx = blockIdx.x*256 + (int)threadIdx.x;
    if (idx >= 462848) return;
    int b = idx / 28928; int j = idx % 28928;
    unsigned off;
    if (j < 14592) {
        int r = j / 7296; int rem = j % 7296;
        int y = r ? 113 : 0;
        off = ((unsigned)(b*114 + y)*114)*64u + (unsigned)rem;
    } else {
        int j2 = j - 14592;
        int y = 1 + j2/128;
        int rem = j2 % 128;
        int xx = (rem >> 6) ? 113 : 0;
        off = (((unsigned)(b*114 + y)*114) + (unsigned)xx)*64u + (unsigned)(rem & 63);
    }
    X3[off] = 0;
}

// generic OIHW -> fragment order [cy][s][mf][lane][8e] (device helper)
template<int CIN,int K>
__device__ __forceinline__ void wcvt_one(const float* __restrict__ w,
                                         ushort* __restrict__ o, int idx) {
    constexpr int NCH = CIN/32, NSTEP = K*K*NCH;
    int e = idx & 7; int t = idx >> 3;
    int lane = t & 63; t >>= 6;
    int mf = t & 3; t >>= 2;
    int s = t % NSTEP; int cy = t / NSTEP;
    int co = cy*64 + mf*16 + (lane & 15);
    int kxy = s / NCH, ch = s % NCH;
    int ci = ch*32 + (lane >> 4)*8 + e;
    int ky = kxy / K, kx = kxy % K;
    o[idx] = f2bf(w[(((size_t)co*CIN + ci)*K + ky)*K + kx]);
}

// all weight conversions in one launch (range dispatch)
__global__ void wcvt_all(const float* __restrict__ w1, ushort* __restrict__ o1,
                         const float* __restrict__ w3, ushort* __restrict__ o3,
                         const float* __restrict__ w4, ushort* __restrict__ o4,
                         const float* __restrict__ w7, ushort* __restrict__ o7,
                         const float* __restrict__ w8, ushort* __restrict__ o8,
                         const float* __restrict__ wu, ushort* __restrict__ ou) {
    int idx = blockIdx.x*256 + (int)threadIdx.x;      // 7,383,040 exactly
    if (idx < 14336) {                                // w1 special (CI4 pack)
        int e = idx & 7; int t = idx >> 3;
        int lane = t & 63; t >>= 6;
        int mf = t & 3; int s = t >> 2;
        int co = mf*16 + (lane & 15);
        int cc = (lane >> 4)*8 + e;
        int kx = cc >> 2, ci = cc & 3;
        float v = 0.f;
        if (kx < 7 && ci < 3) v = w1[(((size_t)co*3 + ci)*7 + s)*7 + kx];
        o1[idx] = f2bf(v);
        return;
    }
    idx -= 14336;
    if (idx < 110592)  { wcvt_one<64,3>(w3, o3, idx);  return; }
    idx -= 110592;
    if (idx < 442368)  { wcvt_one<192,3>(w4, o4, idx); return; }
    idx -= 442368;
    if (idx < 524288)  { wcvt_one<256,2>(w7, o7, idx); return; }
    idx -= 524288;
    if (idx < 2097152) { wcvt_one<512,2>(w8, o8, idx); return; }
    idx -= 2097152;
    wcvt_one<1024,2>(wu, ou, idx);
}

// ---------------------------------------------------------------------------
// maxpool k=5 s=4: XU3 bf16 NHWC (16,10,10,1024) -> pp f32 [b*1024+c][4]
// ---------------------------------------------------------------------------
__global__ void pool54_k(const ushort* __restrict__ in, float* __restrict__ out) {
    int idx = blockIdx.x*256 + (int)threadIdx.x;      // 65536
    int c = idx & 1023; int t = idx >> 10; int q = t & 3; int b = t >> 2;
    int i = q >> 1, j = q & 1;
    float m = -1e30f;
    UNR for (int r=0;r<5;++r)
        UNR for (int cc=0;cc<5;++cc)
            m = fmaxf(m, bf2f(in[(((unsigned)(b*10 + i*4+r))*10 + (unsigned)(j*4+cc))*1024 + c]));
    out[((size_t)(b*1024 + c))*4 + q] = m;
}

// ---------------------------------------------------------------------------
__device__ __forceinline__ void bigrid(int k, int& lo, float& f) {
    float c = ((float)k + 0.5f) * (2.0f/7.0f) - 0.5f;
    c = fminf(fmaxf(c, 0.f), 1.f);
    float fl = floorf(c);
    lo = (int)fl;
    f = c - fl;
}

// bilinear+pad+im2col, x16 vectorized: one thread per (hw,b,c); 2x2 plane
// loaded once as float4; writes 2 x ushort8 (32B contiguous).
__global__ void buildPb2(const float* __restrict__ pp, ushort* __restrict__ Pb) {
    int idx = blockIdx.x*256 + (int)threadIdx.x;   // 802,816 exactly
    int c = idx & 1023;
    int r = idx >> 10;
    int b = r & 15; int hw = r >> 4;
    int h = hw/7, w2 = hw%7;
    f32x4 qv = *(const f32x4*)(pp + ((size_t)(b*1024 + c))*4);
    float q0 = qv[0], q1 = qv[1], q2 = qv[2], q3 = qv[3];
    ushort u[16];
    UNR for (int k=0;k<9;++k) {
        int i = k/3, j = k%3;
        int rr = h + i - 1, cc = w2 + j - 1;
        float val = 0.f;
        if (rr>=0 && rr<7 && cc>=0 && cc<7) {
            int rlo; float rf; bigrid(rr, rlo, rf);
            int clo; float cf; bigrid(cc, clo, cf);
            float top0 = rlo ? q2 : q0, top1 = rlo ? q3 : q1;
            float v0 = clo ? top1 : top0;          // v(rlo, clo)
            float v1 = top1;                       // v(rlo, chi)  (chi = min(clo+1,1))
            float bot0 = q2, bot1 = q3;            // rhi = min(rlo+1,1) = 1 always when rlo=0; =1 when rlo=1
            // rhi row: rlo=0 -> row1 (q2,q3); rlo=1 -> row1 (q2,q3)
            float w0 = clo ? bot1 : bot0;          // v(rhi, clo)
            float w1v = bot1;                      // v(rhi, chi)
            float top = v0*(1.f-cf) + v1*cf;
            float bot = w0*(1.f-cf) + w1v*cf;
            val = top*(1.f-rf) + bot*rf;
        }
        u[k] = f2bf(val);
    }
    UNR for (int k=9;k<16;++k) u[k] = 0;
    ushort* dst = Pb + (size_t)idx*16;
    *(short8v*)dst       = *(short8v*)&u[0];
    *(short8v*)(dst + 8) = *(short8v*)&u[8];
}

// ---------------------------------------------------------------------------
// Fused local-conv, barrier-free wave-partitioned staging (r11 version).
// ---------------------------------------------------------------------------
__global__ __launch_bounds__(256)
void lconv_fused(const float* __restrict__ lcw, const ushort* __restrict__ Pb,
                 float* __restrict__ part) {
    const int bid = (int)blockIdx.x;      // 0..783
    const int xcd = bid & 7;
    const int i   = bid >> 3;             // 0..97
    const int hw  = i % 49;
    const int ks  = xcd + 8*(i/49);       // 0..15, pinned to xcd
    const int t   = (int)threadIdx.x;
    const int lane = t & 63, w = t >> 6;
    const int lm = lane & 15, lk = lane >> 4;
    const int c0 = ks*64;

    __shared__ ushort A[2][8192];         // 2 x 16KB

    auto ldreg = [&](int cc, float (&w9)[2][9]) {
        const int cb = c0 + cc*2;
        UNR for (int cl=0; cl<2; ++cl) {
            const float* src = lcw + ((size_t)(cb+cl)*256 + (unsigned)(w*64+lane))*441
                             + hw*9;
            __builtin_memcpy(w9[cl], src, 36);
        }
    };
    auto wrlds = [&](int buf, float (&w9)[2][9]) {
        UNR for (int cl=0; cl<2; ++cl) {
            int rem = cl*256 + w*64 + lane;
            ushort u[16];
            UNR for (int k=0;k<8;++k) u[k]=f2bf(w9[cl][k]);
            u[8]=f2bf(w9[cl][8]);
            UNR for (int k=9;k<16;++k) u[k]=0;
            *(short8v*)&A[buf][(unsigned)rem*8u] = *(short8v*)&u[0];
            *(short8v*)&A[buf][4096u + (unsigned)rem*8u] = *(short8v*)&u[8];
        }
    };

    f32x4 acc[4];
    UNR for (int q=0;q<4;++q) acc[q] = f32x4{0.f,0.f,0.f,0.f};

    const ushort* Bb = Pb + (size_t)(hw*16 + lm)*16384 + ks*1024 + lk*8;
    const int arow = (lk&1)*512 + (lk>>1)*256 + w*64 + lm;

    auto mmac = [&](int buf, int cc) {
        short8v bv = *(const short8v*)(Bb + cc*32);
        UNR for (int mf = 0; mf < 4; ++mf) {
            short8v av = *(const short8v*)&A[buf][(unsigned)(arow + mf*16)*8u];
            acc[mf] = __builtin_amdgcn_mfma_f32_16x16x32_bf16(av, bv, acc[mf], 0,0,0);
        }
    };

    float wA[2][9], wB[2][9];
    ldreg(0, wA);
    wrlds(0, wA);
    ldreg(1, wB);
    for (int cc = 0; cc < 32; cc += 2) {
        mmac(0, cc);
        wrlds(1, wB);
        if (cc+2 < 32) ldreg(cc+2, wA);
        mmac(1, cc+1);
        if (cc+2 < 32) {
            wrlds(0, wA);
            if (cc+3 < 32) ldreg(cc+3, wB);
        }
    }

    UNR for (int mf=0; mf<4; ++mf)
        UNR for (int r=0;r<4;++r) {
            int o = w*64 + mf*16 + 4*lk + r;
            part[(((size_t)ks*49 + hw)*256 + o)*16 + lm] = acc[mf][r];
        }
}

// part [ks][hw][o][b] -> yact[b][o*49+hw]; 4 b per thread (float4 reads)
__global__ void lreduce2(const float* __restrict__ part, const float* __restrict__ lcb,
                         float* __restrict__ yact) {
    int idx = blockIdx.x*256 + (int)threadIdx.x;  // 50176 exactly
    int b4 = (idx & 3)*4; int o = (idx >> 2) & 255; int hw = idx >> 10;
    f32x4 sum = *(const f32x4*)(part + (((size_t)hw)*256 + o)*16 + b4);
    UNR for (int ks=1; ks<16; ++ks) {
        f32x4 p = *(const f32x4*)(part + (((size_t)ks*49 + hw)*256 + o)*16 + b4);
        UNR for (int r=0;r<4;++r) sum[r] += p[r];
    }
    float bias = lcb[o*49 + hw];
    UNR for (int r=0;r<4;++r) {
        float s = sum[r] + bias;
        yact[(b4+r)*12544 + o*49 + hw] = (s > 0.f) ? s : 0.1f*s;
    }
}

// ---------------------------------------------------------------------------
// FC: float4 weight stream (16B/lane), r19 version.
// ---------------------------------------------------------------------------
__global__ __launch_bounds__(256)
void fc_k(const float* __restrict__ act, const float* __restrict__ fw,
          const float* __restrict__ fb, float* __restrict__ out) {
    __shared__ float red[4][4][16];
    const int t = (int)threadIdx.x;
    const int o0 = blockIdx.x*4;
    float acc[4][16];
    UNR for (int oo=0;oo<4;++oo) UNR for (int b=0;b<16;++b) acc[oo][b]=0.f;

    const int kt = t*4;
    for (int k0 = 0; k0 < 12288; k0 += 1024) {
        int k = k0 + kt;
        f32x4 wv[4];
        UNR for (int oo=0;oo<4;++oo) {
            int o = o0+oo;
            wv[oo] = (o < 4949) ? *(const f32x4*)(fw + (size_t)o*12544 + k)
                                : f32x4{0.f,0.f,0.f,0.f};
        }
        UNR for (int b=0;b<16;++b) {
            f32x4 av = *(const f32x4*)(act + b*12544 + k);
            UNR for (int oo=0;oo<4;++oo) {
                acc[oo][b] = fmaf(wv[oo][0], av[0], acc[oo][b]);
                acc[oo][b] = fmaf(wv[oo][1], av[1], acc[oo][b]);
                acc[oo][b] = fmaf(wv[oo][2], av[2], acc[oo][b]);
                acc[oo][b] = fmaf(wv[oo][3], av[3], acc[oo][b]);
            }
        }
    }
    if (t < 64) {                       // tail k = 12288..12543
        int k = 12288 + kt;
        f32x4 wv[4];
        UNR for (int oo=0;oo<4;++oo) {
            int o = o0+oo;
            wv[oo] = (o < 4949) ? *(const f32x4*)(fw + (size_t)o*12544 + k)
                                : f32x4{0.f,0.f,0.f,0.f};
        }
        UNR for (int b=0;b<16;++b) {
            f32x4 av = *(const f32x4*)(act + b*12544 + k);
            UNR for (int oo=0;oo<4;++oo) {
                acc[oo][b] = fmaf(wv[oo][0], av[0], acc[oo][b]);
                acc[oo][b] = fmaf(wv[oo][1], av[1], acc[oo][b]);
                acc[oo][b] = fmaf(wv[oo][2], av[2], acc[oo][b]);
                acc[oo][b] = fmaf(wv[oo][3], av[3], acc[oo][b]);
            }
        }
    }

    UNR for (int oo=0;oo<4;++oo)
        UNR for (int b=0;b<16;++b) {
            float v = acc[oo][b];
            UNR for (int off=32; off; off>>=1) v += __shfl_xor(v, off, 64);
            acc[oo][b] = v;
        }
    const int wave = t>>6, lane = t&63;
    if (lane == 0)
        UNR for (int oo=0;oo<4;++oo)
            UNR for (int b=0;b<16;++b) red[wave][oo][b] = acc[oo][b];
    __syncthreads();
    if (t < 64) {
        int oo = t>>4, b = t&15;
        float v = red[0][oo][b]+red[1][oo][b]+red[2][oo][b]+red[3][oo][b];
        int o = o0+oo;
        if (o < 4949) out[b*4949 + o] = v + fb[o];
    }
}

// ---------------------------------------------------------------------------
extern "C" void kernel_launch(void* const* d_in, const int* in_sizes, int n_in,
                              void* d_out, int out_size, void* d_ws, size_t ws_size,
                              hipStream_t stream) {
    const float* x   = (const float*)d_in[0];
    const float* w1  = (const float*)d_in[1];
    const float* b1  = (const float*)d_in[2];
    const float* w3  = (const float*)d_in[3];
    const float* b3  = (const float*)d_in[4];
    const float* w4  = (const float*)d_in[5];
    const float* b4  = (const float*)d_in[6];
    const float* w7  = (const float*)d_in[7];
    const float* b7  = (const float*)d_in[8];
    const float* w8  = (const float*)d_in[9];
    const float* b8  = (const float*)d_in[10];
    const float* wu  = (const float*)d_in[11];
    const float* bu  = (const float*)d_in[12];
    const float* lcw = (const float*)d_in[13];
    const float* lcb = (const float*)d_in[14];
    const float* fw  = (const float*)d_in[15];
    const float* fb  = (const float*)d_in[16];
    float* out = (float*)d_out;

    // --- workspace carve (bytes, 256-aligned) ---
    char* base = (char*)d_ws;
    auto alloc = [&](size_t bytes) { char* p = base; base += (bytes + 255) & ~(size_t)255; return p; };
    ushort* X1  = (ushort*)alloc(16u*456*456*4*2);
    ushort* X3  = (ushort*)alloc(16u*114*114*64*2);
    ushort* X4  = (ushort*)alloc(16u*56*56*192*2);
    ushort* X7  = (ushort*)alloc(16u*27*27*256*2);   // later reused as yact
    ushort* X8  = (ushort*)alloc(16u*13*13*512*2);
    ushort* XU1 = (ushort*)alloc(16u*12*12*1024*2);
    ushort* XU2 = (ushort*)alloc(16u*11*11*1024*2);
    ushort* XU3 = (ushort*)alloc(16u*10*10*1024*2);
    ushort* W1b = (ushort*)alloc(64u*224*2);
    ushort* W3b = (ushort*)alloc(192u*576*2);
    ushort* W4b = (ushort*)alloc(256u*1728*2);
    ushort* W7b = (ushort*)alloc(512u*1024*2);
    ushort* W8b = (ushort*)alloc(1024u*2048*2);
    ushort* WUb = (ushort*)alloc(1024u*4096*2);
    float*  pp  = (float*)alloc(16u*1024*4*4);
    ushort* Pb  = (ushort*)alloc((size_t)49*16*16384*2);     // 25.7 MB
    float*  part = (float*)alloc((size_t)16*49*256*16*4);    // 12.8 MB
    float*  partK = (float*)alloc((size_t)4*2304*1024*4);    // 37.7 MB (K-split x4)
    float*  yact = (float*)X7;                               // X7 dead by then

    // --- prep (single wcvt launch) ---
    x1build<<<12996, 256, 0, stream>>>(x, X1);
    x3ring<<<1808, 256, 0, stream>>>(X3);
    wcvt_all<<<28840, 256, 0, stream>>>(w1, W1b, w3, W3b, w4, W4b,
                                        w7, W7b, w8, W8b, wu, WUb);

    // --- conv chain (exact r19 configuration) ---
    convc1<456,456,224,224,114,114,1,64, 4>
        <<<dim3(1,3136), 256, 0, stream>>>(X1, W1b, b1, X3);
    convt<64,3,1,114,114,112,112,192, true,56,56,0,192, 1,4,1, 3,784>
        <<<2352, 256, 0, stream>>>(X3, W3b, b3, X4, nullptr);
    convt<192,3,1,56,56,54,54,256, true,27,27,0,256, 2,2,1>
        <<<dim3(2,365,1), 256, 0, stream>>>(X4, W4b, b4, X7, nullptr);
    convt<256,2,1,27,27,26,26,512, true,13,13,0,512, 2,2,1>
        <<<dim3(4,85,1), 256, 0, stream>>>(X7, W7b, b7, X8, nullptr);
    convt<512,2,1,13,13,12,12,1024, false,12,12,0,1024, 2,2,4>
        <<<dim3(8,18,4), 256, 0, stream>>>(X8, W8b, nullptr, nullptr, partK);
    kreduce<1024,12,12,12,12,1024,4><<<2304, 256, 0, stream>>>(partK, b8, XU1);
    convt<1024,2,1,12,12,11,11,1024, false,11,11,0,1024, 2,2,4>
        <<<dim3(8,16,4), 256, 0, stream>>>(XU1, WUb, nullptr, nullptr, partK);
    kreduce<1024,11,11,11,11,1024,4><<<1936, 256, 0, stream>>>(partK, bu, XU2);
    convt<1024,2,1,11,11,10,10,1024, false,10,10,0,1024, 2,2,4>
        <<<dim3(8,13,4), 256, 0, stream>>>(XU2, WUb, nullptr, nullptr, partK);
    kreduce<1024,10,10,10,10,1024,4><<<1600, 256, 0, stream>>>(partK, bu, XU3);

    // --- head ---
    pool54_k<<<256, 256, 0, stream>>>(XU3, pp);
    buildPb2<<<3136, 256, 0, stream>>>(pp, Pb);
    lconv_fused<<<784, 256, 0, stream>>>(lcw, Pb, part);
    lreduce2<<<196, 256, 0, stream>>>(part, lcb, yact);
    fc_k<<<1238, 256, 0, stream>>>(yact, fw, fb, out);
}

// Round 22
// 707.329 us; speedup vs baseline: 1.0838x; 1.0073x over previous
//
#include <hip/hip_runtime.h>

#define UNR _Pragma("unroll")

typedef __attribute__((ext_vector_type(8))) short short8v;
typedef __attribute__((ext_vector_type(4))) float f32x4;

__device__ __forceinline__ ushort f2bf(float f) {
    union { float f; unsigned u; } x; x.f = f;
    unsigned r = (x.u + 0x7fffu + ((x.u >> 16) & 1u)) >> 16;
    return (ushort)r;
}
__device__ __forceinline__ float bf2f(ushort u) {
    union { unsigned u; float f; } x; x.u = ((unsigned)u) << 16;
    return x.f;
}

// async global->LDS, 16B per lane, dest = wave-uniform base + lane*16
__device__ __forceinline__ void gll16(const ushort* gp, ushort* lp) {
    __builtin_amdgcn_global_load_lds(
        (const __attribute__((address_space(1))) unsigned int*)(const void*)gp,
        (__attribute__((address_space(3))) unsigned int*)(void*)lp, 16, 0, 0);
}

// ---------------------------------------------------------------------------
// conv1 only (CI4): contiguous B, register-pipelined.
// ---------------------------------------------------------------------------
template<int Wp,int Hp,int OW,int OH,int WpN,int HpN,int PADN,int CN,int WAVES>
__global__ __launch_bounds__(WAVES*64)
void convc1(const ushort* __restrict__ Xp, const ushort* __restrict__ Wb,
            const float* __restrict__ bias, ushort* __restrict__ Yp)
{
    constexpr int CIN = 4, STRIDE = 2, NSTEP = 7;
    constexpr int POW = OW/2, POH = OH/2;
    constexpr int NTOT = 16*POW*POH*4;

    const int lane = (int)threadIdx.x & 63;
    const int wave = (int)threadIdx.x >> 6;
    const int n0   = (blockIdx.y*WAVES + wave) * 64;
    const int lm   = lane & 15;
    const int lk   = lane >> 4;

    int ns[4];
    unsigned boff[4];
    UNR for (int nf=0; nf<4; ++nf) {
        int n = n0 + nf*16 + lm;
        if (n > NTOT-1) n = NTOT-1;
        ns[nf] = n;
        int q = n & 3, pp = n >> 2;
        int px = pp % POW; int t = pp / POW;
        int py = t % POH;  int b = t / POH;
        int oy = 2*py + (q>>1), ox = 2*px + (q&1);
        boff[nf] = ((unsigned)(b*Hp + oy*STRIDE)*Wp + (unsigned)(ox*STRIDE))*CIN
                 + 8u*lk;
    }

    f32x4 acc[4][4];
    UNR for (int i=0;i<4;++i) UNR for (int j=0;j<4;++j) acc[i][j] = f32x4{0.f,0.f,0.f,0.f};

    auto ldfr = [&](int s, short8v (&a)[4], short8v (&bf)[4]) {
        const unsigned xoff = (unsigned)(s*Wp*CIN);
        UNR for (int mf=0; mf<4; ++mf)
            a[mf] = *(const short8v*)(Wb + (unsigned)((s*4 + mf)<<9) + (unsigned)lane*8);
        UNR for (int nf=0; nf<4; ++nf)
            bf[nf] = *(const short8v*)(Xp + boff[nf] + xoff);
    };
    auto dm = [&](short8v (&a)[4], short8v (&bf)[4]) {
        UNR for (int mf=0; mf<4; ++mf)
            UNR for (int nf=0; nf<4; ++nf)
                acc[mf][nf] = __builtin_amdgcn_mfma_f32_16x16x32_bf16(
                                  a[mf], bf[nf], acc[mf][nf], 0, 0, 0);
    };

    short8v aA[4], bA[4], aB[4], bB[4];
    ldfr(0, aA, bA);
    for (int sb = 0; sb < NSTEP; sb += 2) {
        if (sb+1 < NSTEP) ldfr(sb+1, aB, bB);
        dm(aA, bA);
        if (sb+2 < NSTEP) ldfr(sb+2, aA, bA);
        if (sb+1 < NSTEP) dm(aB, bB);
    }

    UNR for (int mf=0; mf<4; ++mf) {
        const int co = mf*16 + 4*lk;
        f32x4 bi = *(const f32x4*)(bias + co);
        UNR for (int nf=0; nf<4; ++nf) {
            f32x4 v = acc[mf][nf];
            UNR for (int r=0;r<4;++r) {
                float t2 = v[r] + bi[r];
                t2 = fmaxf(t2, __shfl_xor(t2, 1, 64));
                t2 = fmaxf(t2, __shfl_xor(t2, 2, 64));
                v[r] = t2;
            }
            if ((lane & 3) == 0 && (n0 + nf*16 + lm) < NTOT) {
                int pp = ns[nf] >> 2;
                int px = pp % POW; int t2 = pp / POW;
                int py = t2 % POH; int b = t2 / POH;
                unsigned off = ((unsigned)(b*HpN + py + PADN)*WpN
                                + (unsigned)(px + PADN))*CN + co;
                ushort4 s; s.x=f2bf(v[0]); s.y=f2bf(v[1]); s.z=f2bf(v[2]); s.w=f2bf(v[3]);
                *(ushort4*)(Yp + off) = s;
            }
        }
    }
}

// ---------------------------------------------------------------------------
// Unified MFMA conv, block-cooperative LDS staging (r13 2-buffer structure).
// LINX>0: 1-D grid, XCD-pinned decomposition (bijective when LINX*LINY%8==0).
// SPLITS>1: partials stored as bf16 (ushort4/lane) -> halves partial traffic.
// ---------------------------------------------------------------------------
template<int CIN,int K,int STRIDE,int Wp,int Hp,int OW,int OH,int COUT,
         bool POOL,int WpN,int HpN,int PADN,int CN,int MT,int NT,int SPLITS,
         int LINX=0,int LINY=0>
__global__ __launch_bounds__(256)
void convt(const ushort* __restrict__ Xp, const ushort* __restrict__ Wb,
           const float* __restrict__ bias, ushort* __restrict__ Yp,
           ushort* __restrict__ part)
{
    static_assert(MT*NT == 4, "4 waves");
    constexpr int POW = OW/2, POH = OH/2;
    constexpr int NTOT = POOL ? 16*POW*POH*4 : 16*OW*OH;
    constexpr int NCH = CIN/32, NSTEP = K*K*NCH;
    constexpr int SPS = NSTEP/SPLITS;
    constexpr int CA = MT*4, CB = NT*4, CPW = MT + NT;

    int bx, by;
    if constexpr (LINX > 0) {
        constexpr int CHUNK = LINX*LINY/8;
        int bid = (int)blockIdx.x;
        int p = (bid & 7)*CHUNK + (bid >> 3);
        bx = p % LINX; by = p / LINX;
    } else {
        bx = (int)blockIdx.x; by = (int)blockIdx.y;
    }

    const int t    = (int)threadIdx.x;
    const int lane = t & 63;
    const int w    = t >> 6;
    const int mr   = w / NT, nc = w % NT;
    const int cy0  = bx * MT;
    const int n0b  = by * (NT*64);
    const int nw0  = n0b + nc*64;
    const int lm   = lane & 15, lk = lane >> 4;
    const int s0   = blockIdx.z * SPS, sE = s0 + SPS;

    __shared__ __align__(1024) ushort Ab[2][CA*512];
    __shared__ __align__(1024) ushort Bb[2][CB*512];

    auto nmap = [&](int n, int& b, int& oy, int& ox) {
        if (n > NTOT-1) n = NTOT-1;
        if constexpr (POOL) {
            int q = n & 3, pp = n >> 2;
            int px = pp % POW; int tt = pp / POW;
            int py = tt % POH;  b = tt / POH;
            oy = 2*py + (q>>1); ox = 2*px + (q&1);
        } else {
            ox = n % OW; int tt = n / OW; oy = tt % OH; b = tt / OH;
        }
    };

    int ns[4];
    UNR for (int nf=0; nf<4; ++nf) {
        int n = nw0 + nf*16 + lm;
        if (n > NTOT-1) n = NTOT-1;
        ns[nf] = n;
    }

    unsigned bsrc[CPW];
    UNR for (int j=0; j<CPW; ++j) {
        int q = w*CPW + j;
        if (q >= CA) {
            int bq = q - CA;
            int n = n0b + bq*16 + (lane >> 2);
            int b, oy, ox; nmap(n, b, oy, ox);
            bsrc[j] = ((unsigned)(b*Hp + oy*STRIDE)*Wp + (unsigned)(ox*STRIDE))*CIN
                    + (unsigned)(lane & 3)*8u;
        } else bsrc[j] = 0;
    }

    auto xoffs = [&](int s) -> unsigned {
        int c0  = (s % NCH)*32;
        int kxy = s / NCH;
        int kx  = kxy % K, ky = kxy / K;
        return (unsigned)((ky*Wp + kx)*CIN + c0);
    };
    auto stage = [&](int s, int buf) {
        const unsigned xoff = xoffs(s);
        UNR for (int j=0; j<CPW; ++j) {
            int q = w*CPW + j;
            if (q < CA) {
                const ushort* src = Wb
                    + ((size_t)(((cy0 + (q>>2))*NSTEP + s)*4 + (q&3)) << 9)
                    + (unsigned)lane*8;
                gll16(src, &Ab[buf][(unsigned)q*512u + (unsigned)lane*8u]);
            } else {
                gll16(Xp + bsrc[j] + xoff,
                      &Bb[buf][(unsigned)(q-CA)*512u + (unsigned)lane*8u]);
            }
        }
    };

    f32x4 acc[4][4];
    UNR for (int i=0;i<4;++i) UNR for (int j=0;j<4;++j) acc[i][j] = f32x4{0.f,0.f,0.f,0.f};

    auto compute = [&](int buf) {
        short8v a[4], bf[4];
        UNR for (int mf=0; mf<4; ++mf)
            a[mf] = *(const short8v*)&Ab[buf][(unsigned)((mr*4+mf)*64 + lane)*8u];
        UNR for (int nf=0; nf<4; ++nf)
            bf[nf] = *(const short8v*)&Bb[buf][(unsigned)((nc*64 + nf*16 + lm)*4 + lk)*8u];
        __builtin_amdgcn_s_setprio(1);
        UNR for (int mf=0; mf<4; ++mf)
            UNR for (int nf=0; nf<4; ++nf)
                acc[mf][nf] = __builtin_amdgcn_mfma_f32_16x16x32_bf16(
                                  a[mf], bf[nf], acc[mf][nf], 0, 0, 0);
        __builtin_amdgcn_s_setprio(0);
    };

    stage(s0, 0);
    __syncthreads();
    int buf = 0;
    for (int s = s0; s < sE; ++s) {
        if (s+1 < sE) stage(s+1, buf^1);
        compute(buf);
        __syncthreads();
        buf ^= 1;
    }

    UNR for (int mf=0; mf<4; ++mf) {
        const int co = (cy0 + mr)*64 + mf*16 + 4*lk;
        if constexpr (SPLITS > 1) {
            UNR for (int nf=0; nf<4; ++nf) {
                if ((nw0 + nf*16 + lm) < NTOT) {
                    f32x4 v = acc[mf][nf];
                    ushort4 s2;
                    s2.x = f2bf(v[0]); s2.y = f2bf(v[1]);
                    s2.z = f2bf(v[2]); s2.w = f2bf(v[3]);
                    *(ushort4*)(part + ((size_t)blockIdx.z*NTOT + ns[nf])*COUT + co) = s2;
                }
            }
        } else {
            f32x4 bi = *(const f32x4*)(bias + co);
            UNR for (int nf=0; nf<4; ++nf) {
                f32x4 v = acc[mf][nf];
                UNR for (int r=0;r<4;++r) v[r] += bi[r];
                if constexpr (POOL) {
                    UNR for (int r=0;r<4;++r) {
                        float tt = v[r];
                        tt = fmaxf(tt, __shfl_xor(tt, 1, 64));
                        tt = fmaxf(tt, __shfl_xor(tt, 2, 64));
                        v[r] = tt;
                    }
                    if ((lane & 3) == 0 && (nw0 + nf*16 + lm) < NTOT) {
                        int pp = ns[nf] >> 2;
                        int px = pp % POW; int t2 = pp / POW;
                        int py = t2 % POH; int b = t2 / POH;
                        unsigned off = ((unsigned)(b*HpN + py + PADN)*WpN
                                        + (unsigned)(px + PADN))*CN + co;
                        ushort4 s2; s2.x=f2bf(v[0]); s2.y=f2bf(v[1]); s2.z=f2bf(v[2]); s2.w=f2bf(v[3]);
                        *(ushort4*)(Yp + off) = s2;
                    }
                } else {
                    if ((nw0 + nf*16 + lm) < NTOT) {
                        int n = ns[nf];
                        int ox = n % OW; int t2 = n / OW; int oy = t2 % OH; int b = t2 / OH;
                        unsigned off = ((unsigned)(b*HpN + oy)*WpN + (unsigned)ox)*CN + co;
                        ushort4 s2; s2.x=f2bf(v[0]); s2.y=f2bf(v[1]); s2.z=f2bf(v[2]); s2.w=f2bf(v[3]);
                        *(ushort4*)(Yp + off) = s2;
                    }
                }
            }
        }
    }
}

// part[ks][n][co] (bf16) -> sum + bias -> bf16 NHWC (no pad); 4 co per thread
template<int COUT,int OW,int OH,int WpN,int HpN,int CN,int SPLITS>
__global__ void kreduce(const ushort* __restrict__ part, const float* __restrict__ bias,
                        ushort* __restrict__ Yp) {
    constexpr int NTOT = 16*OW*OH;
    constexpr int C4 = COUT/4;
    int idx = blockIdx.x*256 + (int)threadIdx.x;
    if (idx >= NTOT*C4) return;
    int c4 = (idx % C4)*4; int n = idx / C4;
    float sum[4] = {0.f, 0.f, 0.f, 0.f};
    UNR for (int ks=0; ks<SPLITS; ++ks) {
        ushort4 p = *(const ushort4*)(part + ((size_t)ks*NTOT + n)*COUT + c4);
        sum[0] += bf2f(p.x); sum[1] += bf2f(p.y);
        sum[2] += bf2f(p.z); sum[3] += bf2f(p.w);
    }
    f32x4 bi = *(const f32x4*)(bias + c4);
    int ox = n % OW; int t = n / OW; int oy = t % OH; int b = t / OH;
    ushort4 s;
    s.x = f2bf(sum[0]+bi[0]); s.y = f2bf(sum[1]+bi[1]);
    s.z = f2bf(sum[2]+bi[2]); s.w = f2bf(sum[3]+bi[3]);
    *(ushort4*)(Yp + ((unsigned)(b*HpN + oy)*WpN + (unsigned)ox)*CN + c4) = s;
}

// ---------------------------------------------------------------------------
// x (16,3,448,448) f32 -> full padded X1 bf16 [b][y][x][ci4] (zeros in halo)
// ---------------------------------------------------------------------------
__global__ void x1build(const float* __restrict__ x, ushort* __restrict__ X1) {
    int idx = blockIdx.x*256 + (int)threadIdx.x;      // 16*456*456 = 3,326,976
    int xx = idx % 456; int t = idx/456; int y = t % 456; int b = t/456;
    ushort4 s; s.x = 0; s.y = 0; s.z = 0; s.w = 0;
    if (xx >= 3 && xx < 451 && y >= 3 && y < 451) {
        const float* px = x + ((size_t)b*3*448 + (y-3))*448 + (xx-3);
        s.x = f2bf(px[0]); s.y = f2bf(px[200704]); s.z = f2bf(px[401408]);
    }
    *(ushort4*)(X1 + ((unsigned)(b*456 + y)*456 + (unsigned)xx)*4) = s;
}

// zero X3's pad ring only (rows/cols 0 and 113)
__global__ void x3ring(ushort* __restrict__ X3) {
    int idx = blockIdx.x*256 + (int)threadIdx.x;
    if (idx >= 462848) return;
    int b = idx / 28928; int j = idx % 28928;
    unsigned off;
    if (j < 14592) {
        int r = j / 7296; int rem = j % 7296;
        int y = r ? 113 : 0;
        off = ((unsigned)(b*114 + y)*114)*64u + (unsigned)rem;
    } else {
        int j2 = j - 14592;
        int y = 1 + j2/128;
        int rem = j2 % 128;
        int xx = (rem >> 6) ? 113 : 0;
        off = (((unsigned)(b*114 + y)*114) + (unsigned)xx)*64u + (unsigned)(rem & 63);
    }
    X3[off] = 0;
}

// generic OIHW -> fragment order [cy][s][mf][lane][8e] (device helper)
template<int CIN,int K>
__device__ __forceinline__ void wcvt_one(const float* __restrict__ w,
                                         ushort* __restrict__ o, int idx) {
    constexpr int NCH = CIN/32, NSTEP = K*K*NCH;
    int e = idx & 7; int t = idx >> 3;
    int lane = t & 63; t >>= 6;
    int mf = t & 3; t >>= 2;
    int s = t % NSTEP; int cy = t / NSTEP;
    int co = cy*64 + mf*16 + (lane & 15);
    int kxy = s / NCH, ch = s % NCH;
    int ci = ch*32 + (lane >> 4)*8 + e;
    int ky = kxy / K, kx = kxy % K;
    o[idx] = f2bf(w[(((size_t)co*CIN + ci)*K + ky)*K + kx]);
}

// all weight conversions in one launch (range dispatch)
__global__ void wcvt_all(const float* __restrict__ w1, ushort* __restrict__ o1,
                         const float* __restrict__ w3, ushort* __restrict__ o3,
                         const float* __restrict__ w4, ushort* __restrict__ o4,
                         const float* __restrict__ w7, ushort* __restrict__ o7,
                         const float* __restrict__ w8, ushort* __restrict__ o8,
                         const float* __restrict__ wu, ushort* __restrict__ ou) {
    int idx = blockIdx.x*256 + (int)threadIdx.x;      // 7,383,040 exactly
    if (idx < 14336) {                                // w1 special (CI4 pack)
        int e = idx & 7; int t = idx >> 3;
        int lane = t & 63; t >>= 6;
        int mf = t & 3; int s = t >> 2;
        int co = mf*16 + (lane & 15);
        int cc = (lane >> 4)*8 + e;
        int kx = cc >> 2, ci = cc & 3;
        float v = 0.f;
        if (kx < 7 && ci < 3) v = w1[(((size_t)co*3 + ci)*7 + s)*7 + kx];
        o1[idx] = f2bf(v);
        return;
    }
    idx -= 14336;
    if (idx < 110592)  { wcvt_one<64,3>(w3, o3, idx);  return; }
    idx -= 110592;
    if (idx < 442368)  { wcvt_one<192,3>(w4, o4, idx); return; }
    idx -= 442368;
    if (idx < 524288)  { wcvt_one<256,2>(w7, o7, idx); return; }
    idx -= 524288;
    if (idx < 2097152) { wcvt_one<512,2>(w8, o8, idx); return; }
    idx -= 2097152;
    wcvt_one<1024,2>(wu, ou, idx);
}

// ---------------------------------------------------------------------------
// maxpool k=5 s=4: XU3 bf16 NHWC (16,10,10,1024) -> pp f32 [b*1024+c][4]
// ---------------------------------------------------------------------------
__global__ void pool54_k(const ushort* __restrict__ in, float* __restrict__ out) {
    int idx = blockIdx.x*256 + (int)threadIdx.x;      // 65536
    int c = idx & 1023; int t = idx >> 10; int q = t & 3; int b = t >> 2;
    int i = q >> 1, j = q & 1;
    float m = -1e30f;
    UNR for (int r=0;r<5;++r)
        UNR for (int cc=0;cc<5;++cc)
            m = fmaxf(m, bf2f(in[(((unsigned)(b*10 + i*4+r))*10 + (unsigned)(j*4+cc))*1024 + c]));
    out[((size_t)(b*1024 + c))*4 + q] = m;
}

// ---------------------------------------------------------------------------
__device__ __forceinline__ void bigrid(int k, int& lo, float& f) {
    float c = ((float)k + 0.5f) * (2.0f/7.0f) - 0.5f;
    c = fminf(fmaxf(c, 0.f), 1.f);
    float fl = floorf(c);
    lo = (int)fl;
    f = c - fl;
}

// bilinear+pad+im2col, x16 vectorized: one thread per (hw,b,c); 2x2 plane
// loaded once as float4; writes 2 x ushort8 (32B contiguous).
__global__ void buildPb2(const float* __restrict__ pp, ushort* __restrict__ Pb) {
    int idx = blockIdx.x*256 + (int)threadIdx.x;   // 802,816 exactly
    int c = idx & 1023;
    int r = idx >> 10;
    int b = r & 15; int hw = r >> 4;
    int h = hw/7, w2 = hw%7;
    f32x4 qv = *(const f32x4*)(pp + ((size_t)(b*1024 + c))*4);
    float q0 = qv[0], q1 = qv[1], q2 = qv[2], q3 = qv[3];
    ushort u[16];
    UNR for (int k=0;k<9;++k) {
        int i = k/3, j = k%3;
        int rr = h + i - 1, cc = w2 + j - 1;
        float val = 0.f;
        if (rr>=0 && rr<7 && cc>=0 && cc<7) {
            int rlo; float rf; bigrid(rr, rlo, rf);
            int clo; float cf; bigrid(cc, clo, cf);
            float top0 = rlo ? q2 : q0, top1 = rlo ? q3 : q1;
            float v0 = clo ? top1 : top0;
            float v1 = top1;
            float bot0 = q2, bot1 = q3;
            float w0 = clo ? bot1 : bot0;
            float w1v = bot1;
            float top = v0*(1.f-cf) + v1*cf;
            float bot = w0*(1.f-cf) + w1v*cf;
            val = top*(1.f-rf) + bot*rf;
        }
        u[k] = f2bf(val);
    }
    UNR for (int k=9;k<16;++k) u[k] = 0;
    ushort* dst = Pb + (size_t)idx*16;
    *(short8v*)dst       = *(short8v*)&u[0];
    *(short8v*)(dst + 8) = *(short8v*)&u[8];
}

// ---------------------------------------------------------------------------
// Fused local-conv, barrier-free wave-partitioned staging (r11 version).
// ---------------------------------------------------------------------------
__global__ __launch_bounds__(256)
void lconv_fused(const float* __restrict__ lcw, const ushort* __restrict__ Pb,
                 float* __restrict__ part) {
    const int bid = (int)blockIdx.x;      // 0..783
    const int xcd = bid & 7;
    const int i   = bid >> 3;             // 0..97
    const int hw  = i % 49;
    const int ks  = xcd + 8*(i/49);       // 0..15, pinned to xcd
    const int t   = (int)threadIdx.x;
    const int lane = t & 63, w = t >> 6;
    const int lm = lane & 15, lk = lane >> 4;
    const int c0 = ks*64;

    __shared__ ushort A[2][8192];         // 2 x 16KB

    auto ldreg = [&](int cc, float (&w9)[2][9]) {
        const int cb = c0 + cc*2;
        UNR for (int cl=0; cl<2; ++cl) {
            const float* src = lcw + ((size_t)(cb+cl)*256 + (unsigned)(w*64+lane))*441
                             + hw*9;
            __builtin_memcpy(w9[cl], src, 36);
        }
    };
    auto wrlds = [&](int buf, float (&w9)[2][9]) {
        UNR for (int cl=0; cl<2; ++cl) {
            int rem = cl*256 + w*64 + lane;
            ushort u[16];
            UNR for (int k=0;k<8;++k) u[k]=f2bf(w9[cl][k]);
            u[8]=f2bf(w9[cl][8]);
            UNR for (int k=9;k<16;++k) u[k]=0;
            *(short8v*)&A[buf][(unsigned)rem*8u] = *(short8v*)&u[0];
            *(short8v*)&A[buf][4096u + (unsigned)rem*8u] = *(short8v*)&u[8];
        }
    };

    f32x4 acc[4];
    UNR for (int q=0;q<4;++q) acc[q] = f32x4{0.f,0.f,0.f,0.f};

    const ushort* Bb = Pb + (size_t)(hw*16 + lm)*16384 + ks*1024 + lk*8;
    const int arow = (lk&1)*512 + (lk>>1)*256 + w*64 + lm;

    auto mmac = [&](int buf, int cc) {
        short8v bv = *(const short8v*)(Bb + cc*32);
        UNR for (int mf = 0; mf < 4; ++mf) {
            short8v av = *(const short8v*)&A[buf][(unsigned)(arow + mf*16)*8u];
            acc[mf] = __builtin_amdgcn_mfma_f32_16x16x32_bf16(av, bv, acc[mf], 0,0,0);
        }
    };

    float wA[2][9], wB[2][9];
    ldreg(0, wA);
    wrlds(0, wA);
    ldreg(1, wB);
    for (int cc = 0; cc < 32; cc += 2) {
        mmac(0, cc);
        wrlds(1, wB);
        if (cc+2 < 32) ldreg(cc+2, wA);
        mmac(1, cc+1);
        if (cc+2 < 32) {
            wrlds(0, wA);
            if (cc+3 < 32) ldreg(cc+3, wB);
        }
    }

    UNR for (int mf=0; mf<4; ++mf)
        UNR for (int r=0;r<4;++r) {
            int o = w*64 + mf*16 + 4*lk + r;
            part[(((size_t)ks*49 + hw)*256 + o)*16 + lm] = acc[mf][r];
        }
}

// part [ks][hw][o][b] -> yact[b][o*49+hw]; 4 b per thread (float4 reads)
__global__ void lreduce2(const float* __restrict__ part, const float* __restrict__ lcb,
                         float* __restrict__ yact) {
    int idx = blockIdx.x*256 + (int)threadIdx.x;  // 50176 exactly
    int b4 = (idx & 3)*4; int o = (idx >> 2) & 255; int hw = idx >> 10;
    f32x4 sum = *(const f32x4*)(part + (((size_t)hw)*256 + o)*16 + b4);
    UNR for (int ks=1; ks<16; ++ks) {
        f32x4 p = *(const f32x4*)(part + (((size_t)ks*49 + hw)*256 + o)*16 + b4);
        UNR for (int r=0;r<4;++r) sum[r] += p[r];
    }
    float bias = lcb[o*49 + hw];
    UNR for (int r=0;r<4;++r) {
        float s = sum[r] + bias;
        yact[(b4+r)*12544 + o*49 + hw] = (s > 0.f) ? s : 0.1f*s;
    }
}

// ---------------------------------------------------------------------------
// FC: float4 weight stream (16B/lane), r19 version.
// ---------------------------------------------------------------------------
__global__ __launch_bounds__(256)
void fc_k(const float* __restrict__ act, const float* __restrict__ fw,
          const float* __restrict__ fb, float* __restrict__ out) {
    __shared__ float red[4][4][16];
    const int t = (int)threadIdx.x;
    const int o0 = blockIdx.x*4;
    float acc[4][16];
    UNR for (int oo=0;oo<4;++oo) UNR for (int b=0;b<16;++b) acc[oo][b]=0.f;

    const int kt = t*4;
    for (int k0 = 0; k0 < 12288; k0 += 1024) {
        int k = k0 + kt;
        f32x4 wv[4];
        UNR for (int oo=0;oo<4;++oo) {
            int o = o0+oo;
            wv[oo] = (o < 4949) ? *(const f32x4*)(fw + (size_t)o*12544 + k)
                                : f32x4{0.f,0.f,0.f,0.f};
        }
        UNR for (int b=0;b<16;++b) {
            f32x4 av = *(const f32x4*)(act + b*12544 + k);
            UNR for (int oo=0;oo<4;++oo) {
                acc[oo][b] = fmaf(wv[oo][0], av[0], acc[oo][b]);
                acc[oo][b] = fmaf(wv[oo][1], av[1], acc[oo][b]);
                acc[oo][b] = fmaf(wv[oo][2], av[2], acc[oo][b]);
                acc[oo][b] = fmaf(wv[oo][3], av[3], acc[oo][b]);
            }
        }
    }
    if (t < 64) {                       // tail k = 12288..12543
        int k = 12288 + kt;
        f32x4 wv[4];
        UNR for (int oo=0;oo<4;++oo) {
            int o = o0+oo;
            wv[oo] = (o < 4949) ? *(const f32x4*)(fw + (size_t)o*12544 + k)
                                : f32x4{0.f,0.f,0.f,0.f};
        }
        UNR for (int b=0;b<16;++b) {
            f32x4 av = *(const f32x4*)(act + b*12544 + k);
            UNR for (int oo=0;oo<4;++oo) {
                acc[oo][b] = fmaf(wv[oo][0], av[0], acc[oo][b]);
                acc[oo][b] = fmaf(wv[oo][1], av[1], acc[oo][b]);
                acc[oo][b] = fmaf(wv[oo][2], av[2], acc[oo][b]);
                acc[oo][b] = fmaf(wv[oo][3], av[3], acc[oo][b]);
            }
        }
    }

    UNR for (int oo=0;oo<4;++oo)
        UNR for (int b=0;b<16;++b) {
            float v = acc[oo][b];
            UNR for (int off=32; off; off>>=1) v += __shfl_xor(v, off, 64);
            acc[oo][b] = v;
        }
    const int wave = t>>6, lane = t&63;
    if (lane == 0)
        UNR for (int oo=0;oo<4;++oo)
            UNR for (int b=0;b<16;++b) red[wave][oo][b] = acc[oo][b];
    __syncthreads();
    if (t < 64) {
        int oo = t>>4, b = t&15;
        float v = red[0][oo][b]+red[1][oo][b]+red[2][oo][b]+red[3][oo][b];
        int o = o0+oo;
        if (o < 4949) out[b*4949 + o] = v + fb[o];
    }
}

// ---------------------------------------------------------------------------
extern "C" void kernel_launch(void* const* d_in, const int* in_sizes, int n_in,
                              void* d_out, int out_size, void* d_ws, size_t ws_size,
                              hipStream_t stream) {
    const float* x   = (const float*)d_in[0];
    const float* w1  = (const float*)d_in[1];
    const float* b1  = (const float*)d_in[2];
    const float* w3  = (const float*)d_in[3];
    const float* b3  = (const float*)d_in[4];
    const float* w4  = (const float*)d_in[5];
    const float* b4  = (const float*)d_in[6];
    const float* w7  = (const float*)d_in[7];
    const float* b7  = (const float*)d_in[8];
    const float* w8  = (const float*)d_in[9];
    const float* b8  = (const float*)d_in[10];
    const float* wu  = (const float*)d_in[11];
    const float* bu  = (const float*)d_in[12];
    const float* lcw = (const float*)d_in[13];
    const float* lcb = (const float*)d_in[14];
    const float* fw  = (const float*)d_in[15];
    const float* fb  = (const float*)d_in[16];
    float* out = (float*)d_out;

    // --- workspace carve (bytes, 256-aligned) ---
    char* base = (char*)d_ws;
    auto alloc = [&](size_t bytes) { char* p = base; base += (bytes + 255) & ~(size_t)255; return p; };
    ushort* X1  = (ushort*)alloc(16u*456*456*4*2);
    ushort* X3  = (ushort*)alloc(16u*114*114*64*2);
    ushort* X4  = (ushort*)alloc(16u*56*56*192*2);
    ushort* X7  = (ushort*)alloc(16u*27*27*256*2);   // later reused as yact
    ushort* X8  = (ushort*)alloc(16u*13*13*512*2);
    ushort* XU1 = (ushort*)alloc(16u*12*12*1024*2);
    ushort* XU2 = (ushort*)alloc(16u*11*11*1024*2);
    ushort* XU3 = (ushort*)alloc(16u*10*10*1024*2);
    ushort* W1b = (ushort*)alloc(64u*224*2);
    ushort* W3b = (ushort*)alloc(192u*576*2);
    ushort* W4b = (ushort*)alloc(256u*1728*2);
    ushort* W7b = (ushort*)alloc(512u*1024*2);
    ushort* W8b = (ushort*)alloc(1024u*2048*2);
    ushort* WUb = (ushort*)alloc(1024u*4096*2);
    float*  pp  = (float*)alloc(16u*1024*4*4);
    ushort* Pb  = (ushort*)alloc((size_t)49*16*16384*2);     // 25.7 MB
    float*  part = (float*)alloc((size_t)16*49*256*16*4);    // 12.8 MB
    ushort* partK = (ushort*)alloc((size_t)4*2304*1024*2);   // 18.9 MB (bf16 K-split)
    float*  yact = (float*)X7;                               // X7 dead by then

    // --- prep (single wcvt launch) ---
    x1build<<<12996, 256, 0, stream>>>(x, X1);
    x3ring<<<1808, 256, 0, stream>>>(X3);
    wcvt_all<<<28840, 256, 0, stream>>>(w1, W1b, w3, W3b, w4, W4b,
                                        w7, W7b, w8, W8b, wu, WUb);

    // --- conv chain ---
    convc1<456,456,224,224,114,114,1,64, 4>
        <<<dim3(1,3136), 256, 0, stream>>>(X1, W1b, b1, X3);
    convt<64,3,1,114,114,112,112,192, true,56,56,0,192, 1,4,1, 3,784>
        <<<2352, 256, 0, stream>>>(X3, W3b, b3, X4, nullptr);
    convt<192,3,1,56,56,54,54,256, true,27,27,0,256, 2,2,1>
        <<<dim3(2,365,1), 256, 0, stream>>>(X4, W4b, b4, X7, nullptr);
    convt<256,2,1,27,27,26,26,512, true,13,13,0,512, 2,2,1>
        <<<dim3(4,85,1), 256, 0, stream>>>(X7, W7b, b7, X8, nullptr);
    convt<512,2,1,13,13,12,12,1024, false,12,12,0,1024, 2,2,4>
        <<<dim3(8,18,4), 256, 0, stream>>>(X8, W8b, nullptr, nullptr, partK);
    kreduce<1024,12,12,12,12,1024,4><<<2304, 256, 0, stream>>>(partK, b8, XU1);
    convt<1024,2,1,12,12,11,11,1024, false,11,11,0,1024, 2,2,4>
        <<<dim3(8,16,4), 256, 0, stream>>>(XU1, WUb, nullptr, nullptr, partK);
    kreduce<1024,11,11,11,11,1024,4><<<1936, 256, 0, stream>>>(partK, bu, XU2);
    convt<1024,2,1,11,11,10,10,1024, false,10,10,0,1024, 2,2,4>
        <<<dim3(8,13,4), 256, 0, stream>>>(XU2, WUb, nullptr, nullptr, partK);
    kreduce<1024,10,10,10,10,1024,4><<<1600, 256, 0, stream>>>(partK, bu, XU3);

    // --- head ---
    pool54_k<<<256, 256, 0, stream>>>(XU3, pp);
    buildPb2<<<3136, 256, 0, stream>>>(pp, Pb);
    lconv_fused<<<784, 256, 0, stream>>>(lcw, Pb, part);
    lreduce2<<<196, 256, 0, stream>>>(part, lcb, yact);
    fc_k<<<1238, 256, 0, stream>>>(yact, fw, fb, out);
}

// Round 23
// 700.596 us; speedup vs baseline: 1.0942x; 1.0096x over previous
//
#include <hip/hip_runtime.h>

#define UNR _Pragma("unroll")

typedef __attribute__((ext_vector_type(8))) short short8v;
typedef __attribute__((ext_vector_type(4))) float f32x4;

__device__ __forceinline__ ushort f2bf(float f) {
    union { float f; unsigned u; } x; x.f = f;
    unsigned r = (x.u + 0x7fffu + ((x.u >> 16) & 1u)) >> 16;
    return (ushort)r;
}
__device__ __forceinline__ float bf2f(ushort u) {
    union { unsigned u; float f; } x; x.u = ((unsigned)u) << 16;
    return x.f;
}

// async global->LDS, 16B per lane, dest = wave-uniform base + lane*16
__device__ __forceinline__ void gll16(const ushort* gp, ushort* lp) {
    __builtin_amdgcn_global_load_lds(
        (const __attribute__((address_space(1))) unsigned int*)(const void*)gp,
        (__attribute__((address_space(3))) unsigned int*)(void*)lp, 16, 0, 0);
}

// ---------------------------------------------------------------------------
// conv1 only (CI4): contiguous B, register-pipelined.
// ---------------------------------------------------------------------------
template<int Wp,int Hp,int OW,int OH,int WpN,int HpN,int PADN,int CN,int WAVES>
__global__ __launch_bounds__(WAVES*64)
void convc1(const ushort* __restrict__ Xp, const ushort* __restrict__ Wb,
            const float* __restrict__ bias, ushort* __restrict__ Yp)
{
    constexpr int CIN = 4, STRIDE = 2, NSTEP = 7;
    constexpr int POW = OW/2, POH = OH/2;
    constexpr int NTOT = 16*POW*POH*4;

    const int lane = (int)threadIdx.x & 63;
    const int wave = (int)threadIdx.x >> 6;
    const int n0   = (blockIdx.y*WAVES + wave) * 64;
    const int lm   = lane & 15;
    const int lk   = lane >> 4;

    int ns[4];
    unsigned boff[4];
    UNR for (int nf=0; nf<4; ++nf) {
        int n = n0 + nf*16 + lm;
        if (n > NTOT-1) n = NTOT-1;
        ns[nf] = n;
        int q = n & 3, pp = n >> 2;
        int px = pp % POW; int t = pp / POW;
        int py = t % POH;  int b = t / POH;
        int oy = 2*py + (q>>1), ox = 2*px + (q&1);
        boff[nf] = ((unsigned)(b*Hp + oy*STRIDE)*Wp + (unsigned)(ox*STRIDE))*CIN
                 + 8u*lk;
    }

    f32x4 acc[4][4];
    UNR for (int i=0;i<4;++i) UNR for (int j=0;j<4;++j) acc[i][j] = f32x4{0.f,0.f,0.f,0.f};

    auto ldfr = [&](int s, short8v (&a)[4], short8v (&bf)[4]) {
        const unsigned xoff = (unsigned)(s*Wp*CIN);
        UNR for (int mf=0; mf<4; ++mf)
            a[mf] = *(const short8v*)(Wb + (unsigned)((s*4 + mf)<<9) + (unsigned)lane*8);
        UNR for (int nf=0; nf<4; ++nf)
            bf[nf] = *(const short8v*)(Xp + boff[nf] + xoff);
    };
    auto dm = [&](short8v (&a)[4], short8v (&bf)[4]) {
        UNR for (int mf=0; mf<4; ++mf)
            UNR for (int nf=0; nf<4; ++nf)
                acc[mf][nf] = __builtin_amdgcn_mfma_f32_16x16x32_bf16(
                                  a[mf], bf[nf], acc[mf][nf], 0, 0, 0);
    };

    short8v aA[4], bA[4], aB[4], bB[4];
    ldfr(0, aA, bA);
    for (int sb = 0; sb < NSTEP; sb += 2) {
        if (sb+1 < NSTEP) ldfr(sb+1, aB, bB);
        dm(aA, bA);
        if (sb+2 < NSTEP) ldfr(sb+2, aA, bA);
        if (sb+1 < NSTEP) dm(aB, bB);
    }

    UNR for (int mf=0; mf<4; ++mf) {
        const int co = mf*16 + 4*lk;
        f32x4 bi = *(const f32x4*)(bias + co);
        UNR for (int nf=0; nf<4; ++nf) {
            f32x4 v = acc[mf][nf];
            UNR for (int r=0;r<4;++r) {
                float t2 = v[r] + bi[r];
                t2 = fmaxf(t2, __shfl_xor(t2, 1, 64));
                t2 = fmaxf(t2, __shfl_xor(t2, 2, 64));
                v[r] = t2;
            }
            if ((lane & 3) == 0 && (n0 + nf*16 + lm) < NTOT) {
                int pp = ns[nf] >> 2;
                int px = pp % POW; int t2 = pp / POW;
                int py = t2 % POH; int b = t2 / POH;
                unsigned off = ((unsigned)(b*HpN + py + PADN)*WpN
                                + (unsigned)(px + PADN))*CN + co;
                ushort4 s; s.x=f2bf(v[0]); s.y=f2bf(v[1]); s.z=f2bf(v[2]); s.w=f2bf(v[3]);
                *(ushort4*)(Yp + off) = s;
            }
        }
    }
}

// ---------------------------------------------------------------------------
// Unified MFMA conv, block-cooperative LDS staging (r13 2-buffer structure).
// LINX>0: 1-D grid, XCD-pinned decomposition (bijective when LINX*LINY%8==0).
// SPLITS>1: partials stored as bf16 (ushort4/lane).
// ---------------------------------------------------------------------------
template<int CIN,int K,int STRIDE,int Wp,int Hp,int OW,int OH,int COUT,
         bool POOL,int WpN,int HpN,int PADN,int CN,int MT,int NT,int SPLITS,
         int LINX=0,int LINY=0>
__global__ __launch_bounds__(256)
void convt(const ushort* __restrict__ Xp, const ushort* __restrict__ Wb,
           const float* __restrict__ bias, ushort* __restrict__ Yp,
           ushort* __restrict__ part)
{
    static_assert(MT*NT == 4, "4 waves");
    constexpr int POW = OW/2, POH = OH/2;
    constexpr int NTOT = POOL ? 16*POW*POH*4 : 16*OW*OH;
    constexpr int NCH = CIN/32, NSTEP = K*K*NCH;
    constexpr int SPS = NSTEP/SPLITS;
    constexpr int CA = MT*4, CB = NT*4, CPW = MT + NT;

    int bx, by;
    if constexpr (LINX > 0) {
        constexpr int CHUNK = LINX*LINY/8;
        int bid = (int)blockIdx.x;
        int p = (bid & 7)*CHUNK + (bid >> 3);
        bx = p % LINX; by = p / LINX;
    } else {
        bx = (int)blockIdx.x; by = (int)blockIdx.y;
    }

    const int t    = (int)threadIdx.x;
    const int lane = t & 63;
    const int w    = t >> 6;
    const int mr   = w / NT, nc = w % NT;
    const int cy0  = bx * MT;
    const int n0b  = by * (NT*64);
    const int nw0  = n0b + nc*64;
    const int lm   = lane & 15, lk = lane >> 4;
    const int s0   = blockIdx.z * SPS, sE = s0 + SPS;

    __shared__ __align__(1024) ushort Ab[2][CA*512];
    __shared__ __align__(1024) ushort Bb[2][CB*512];

    auto nmap = [&](int n, int& b, int& oy, int& ox) {
        if (n > NTOT-1) n = NTOT-1;
        if constexpr (POOL) {
            int q = n & 3, pp = n >> 2;
            int px = pp % POW; int tt = pp / POW;
            int py = tt % POH;  b = tt / POH;
            oy = 2*py + (q>>1); ox = 2*px + (q&1);
        } else {
            ox = n % OW; int tt = n / OW; oy = tt % OH; b = tt / OH;
        }
    };

    int ns[4];
    UNR for (int nf=0; nf<4; ++nf) {
        int n = nw0 + nf*16 + lm;
        if (n > NTOT-1) n = NTOT-1;
        ns[nf] = n;
    }

    unsigned bsrc[CPW];
    UNR for (int j=0; j<CPW; ++j) {
        int q = w*CPW + j;
        if (q >= CA) {
            int bq = q - CA;
            int n = n0b + bq*16 + (lane >> 2);
            int b, oy, ox; nmap(n, b, oy, ox);
            bsrc[j] = ((unsigned)(b*Hp + oy*STRIDE)*Wp + (unsigned)(ox*STRIDE))*CIN
                    + (unsigned)(lane & 3)*8u;
        } else bsrc[j] = 0;
    }

    auto xoffs = [&](int s) -> unsigned {
        int c0  = (s % NCH)*32;
        int kxy = s / NCH;
        int kx  = kxy % K, ky = kxy / K;
        return (unsigned)((ky*Wp + kx)*CIN + c0);
    };
    auto stage = [&](int s, int buf) {
        const unsigned xoff = xoffs(s);
        UNR for (int j=0; j<CPW; ++j) {
            int q = w*CPW + j;
            if (q < CA) {
                const ushort* src = Wb
                    + ((size_t)(((cy0 + (q>>2))*NSTEP + s)*4 + (q&3)) << 9)
                    + (unsigned)lane*8;
                gll16(src, &Ab[buf][(unsigned)q*512u + (unsigned)lane*8u]);
            } else {
                gll16(Xp + bsrc[j] + xoff,
                      &Bb[buf][(unsigned)(q-CA)*512u + (unsigned)lane*8u]);
            }
        }
    };

    f32x4 acc[4][4];
    UNR for (int i=0;i<4;++i) UNR for (int j=0;j<4;++j) acc[i][j] = f32x4{0.f,0.f,0.f,0.f};

    auto compute = [&](int buf) {
        short8v a[4], bf[4];
        UNR for (int mf=0; mf<4; ++mf)
            a[mf] = *(const short8v*)&Ab[buf][(unsigned)((mr*4+mf)*64 + lane)*8u];
        UNR for (int nf=0; nf<4; ++nf)
            bf[nf] = *(const short8v*)&Bb[buf][(unsigned)((nc*64 + nf*16 + lm)*4 + lk)*8u];
        __builtin_amdgcn_s_setprio(1);
        UNR for (int mf=0; mf<4; ++mf)
            UNR for (int nf=0; nf<4; ++nf)
                acc[mf][nf] = __builtin_amdgcn_mfma_f32_16x16x32_bf16(
                                  a[mf], bf[nf], acc[mf][nf], 0, 0, 0);
        __builtin_amdgcn_s_setprio(0);
    };

    stage(s0, 0);
    __syncthreads();
    int buf = 0;
    for (int s = s0; s < sE; ++s) {
        if (s+1 < sE) stage(s+1, buf^1);
        compute(buf);
        __syncthreads();
        buf ^= 1;
    }

    UNR for (int mf=0; mf<4; ++mf) {
        const int co = (cy0 + mr)*64 + mf*16 + 4*lk;
        if constexpr (SPLITS > 1) {
            UNR for (int nf=0; nf<4; ++nf) {
                if ((nw0 + nf*16 + lm) < NTOT) {
                    f32x4 v = acc[mf][nf];
                    ushort4 s2;
                    s2.x = f2bf(v[0]); s2.y = f2bf(v[1]);
                    s2.z = f2bf(v[2]); s2.w = f2bf(v[3]);
                    *(ushort4*)(part + ((size_t)blockIdx.z*NTOT + ns[nf])*COUT + co) = s2;
                }
            }
        } else {
            f32x4 bi = *(const f32x4*)(bias + co);
            UNR for (int nf=0; nf<4; ++nf) {
                f32x4 v = acc[mf][nf];
                UNR for (int r=0;r<4;++r) v[r] += bi[r];
                if constexpr (POOL) {
                    UNR for (int r=0;r<4;++r) {
                        float tt = v[r];
                        tt = fmaxf(tt, __shfl_xor(tt, 1, 64));
                        tt = fmaxf(tt, __shfl_xor(tt, 2, 64));
                        v[r] = tt;
                    }
                    if ((lane & 3) == 0 && (nw0 + nf*16 + lm) < NTOT) {
                        int pp = ns[nf] >> 2;
                        int px = pp % POW; int t2 = pp / POW;
                        int py = t2 % POH; int b = t2 / POH;
                        unsigned off = ((unsigned)(b*HpN + py + PADN)*WpN
                                        + (unsigned)(px + PADN))*CN + co;
                        ushort4 s2; s2.x=f2bf(v[0]); s2.y=f2bf(v[1]); s2.z=f2bf(v[2]); s2.w=f2bf(v[3]);
                        *(ushort4*)(Yp + off) = s2;
                    }
                } else {
                    if ((nw0 + nf*16 + lm) < NTOT) {
                        int n = ns[nf];
                        int ox = n % OW; int t2 = n / OW; int oy = t2 % OH; int b = t2 / OH;
                        unsigned off = ((unsigned)(b*HpN + oy)*WpN + (unsigned)ox)*CN + co;
                        ushort4 s2; s2.x=f2bf(v[0]); s2.y=f2bf(v[1]); s2.z=f2bf(v[2]); s2.w=f2bf(v[3]);
                        *(ushort4*)(Yp + off) = s2;
                    }
                }
            }
        }
    }
}

// part[ks][n][co] (bf16) -> sum + bias -> bf16 NHWC (no pad); 4 co per thread
template<int COUT,int OW,int OH,int WpN,int HpN,int CN,int SPLITS>
__global__ void kreduce(const ushort* __restrict__ part, const float* __restrict__ bias,
                        ushort* __restrict__ Yp) {
    constexpr int NTOT = 16*OW*OH;
    constexpr int C4 = COUT/4;
    int idx = blockIdx.x*256 + (int)threadIdx.x;
    if (idx >= NTOT*C4) return;
    int c4 = (idx % C4)*4; int n = idx / C4;
    float sum[4] = {0.f, 0.f, 0.f, 0.f};
    UNR for (int ks=0; ks<SPLITS; ++ks) {
        ushort4 p = *(const ushort4*)(part + ((size_t)ks*NTOT + n)*COUT + c4);
        sum[0] += bf2f(p.x); sum[1] += bf2f(p.y);
        sum[2] += bf2f(p.z); sum[3] += bf2f(p.w);
    }
    f32x4 bi = *(const f32x4*)(bias + c4);
    int ox = n % OW; int t = n / OW; int oy = t % OH; int b = t / OH;
    ushort4 s;
    s.x = f2bf(sum[0]+bi[0]); s.y = f2bf(sum[1]+bi[1]);
    s.z = f2bf(sum[2]+bi[2]); s.w = f2bf(sum[3]+bi[3]);
    *(ushort4*)(Yp + ((unsigned)(b*HpN + oy)*WpN + (unsigned)ox)*CN + c4) = s;
}

// ---------------------------------------------------------------------------
// megaprep: x1build + x3ring + all weight conversions in ONE launch.
// ---------------------------------------------------------------------------
template<int CIN,int K>
__device__ __forceinline__ void wcvt_one(const float* __restrict__ w,
                                         ushort* __restrict__ o, int idx) {
    constexpr int NCH = CIN/32, NSTEP = K*K*NCH;
    int e = idx & 7; int t = idx >> 3;
    int lane = t & 63; t >>= 6;
    int mf = t & 3; t >>= 2;
    int s = t % NSTEP; int cy = t / NSTEP;
    int co = cy*64 + mf*16 + (lane & 15);
    int kxy = s / NCH, ch = s % NCH;
    int ci = ch*32 + (lane >> 4)*8 + e;
    int ky = kxy / K, kx = kxy % K;
    o[idx] = f2bf(w[(((size_t)co*CIN + ci)*K + ky)*K + kx]);
}

__global__ void megaprep(const float* __restrict__ x,  ushort* __restrict__ X1,
                         ushort* __restrict__ X3,
                         const float* __restrict__ w1, ushort* __restrict__ o1,
                         const float* __restrict__ w3, ushort* __restrict__ o3,
                         const float* __restrict__ w4, ushort* __restrict__ o4,
                         const float* __restrict__ w7, ushort* __restrict__ o7,
                         const float* __restrict__ w8, ushort* __restrict__ o8,
                         const float* __restrict__ wu, ushort* __restrict__ ou) {
    int idx = blockIdx.x*256 + (int)threadIdx.x;      // 11,172,864 exactly
    // --- x1build: 3,326,976 ---
    if (idx < 3326976) {
        int xx = idx % 456; int t = idx/456; int y = t % 456; int b = t/456;
        ushort4 s; s.x = 0; s.y = 0; s.z = 0; s.w = 0;
        if (xx >= 3 && xx < 451 && y >= 3 && y < 451) {
            const float* px = x + ((size_t)b*3*448 + (y-3))*448 + (xx-3);
            s.x = f2bf(px[0]); s.y = f2bf(px[200704]); s.z = f2bf(px[401408]);
        }
        *(ushort4*)(X1 + ((unsigned)(b*456 + y)*456 + (unsigned)xx)*4) = s;
        return;
    }
    idx -= 3326976;
    // --- x3ring: 462,848 ---
    if (idx < 462848) {
        int b = idx / 28928; int j = idx % 28928;
        unsigned off;
        if (j < 14592) {
            int r = j / 7296; int rem = j % 7296;
            int y = r ? 113 : 0;
            off = ((unsigned)(b*114 + y)*114)*64u + (unsigned)rem;
        } else {
            int j2 = j - 14592;
            int y = 1 + j2/128;
            int rem = j2 % 128;
            int xx = (rem >> 6) ? 113 : 0;
            off = (((unsigned)(b*114 + y)*114) + (unsigned)xx)*64u + (unsigned)(rem & 63);
        }
        X3[off] = 0;
        return;
    }
    idx -= 462848;
    // --- w1 special (CI4 pack): 14,336 ---
    if (idx < 14336) {
        int e = idx & 7; int t = idx >> 3;
        int lane = t & 63; t >>= 6;
        int mf = t & 3; int s = t >> 2;
        int co = mf*16 + (lane & 15);
        int cc = (lane >> 4)*8 + e;
        int kx = cc >> 2, ci = cc & 3;
        float v = 0.f;
        if (kx < 7 && ci < 3) v = w1[(((size_t)co*3 + ci)*7 + s)*7 + kx];
        o1[idx] = f2bf(v);
        return;
    }
    idx -= 14336;
    if (idx < 110592)  { wcvt_one<64,3>(w3, o3, idx);  return; }
    idx -= 110592;
    if (idx < 442368)  { wcvt_one<192,3>(w4, o4, idx); return; }
    idx -= 442368;
    if (idx < 524288)  { wcvt_one<256,2>(w7, o7, idx); return; }
    idx -= 524288;
    if (idx < 2097152) { wcvt_one<512,2>(w8, o8, idx); return; }
    idx -= 2097152;
    wcvt_one<1024,2>(wu, ou, idx);
}

// ---------------------------------------------------------------------------
// maxpool k=5 s=4: XU3 bf16 NHWC (16,10,10,1024) -> pp f32 [b*1024+c][4]
// ---------------------------------------------------------------------------
__global__ void pool54_k(const ushort* __restrict__ in, float* __restrict__ out) {
    int idx = blockIdx.x*256 + (int)threadIdx.x;      // 65536
    int c = idx & 1023; int t = idx >> 10; int q = t & 3; int b = t >> 2;
    int i = q >> 1, j = q & 1;
    float m = -1e30f;
    UNR for (int r=0;r<5;++r)
        UNR for (int cc=0;cc<5;++cc)
            m = fmaxf(m, bf2f(in[(((unsigned)(b*10 + i*4+r))*10 + (unsigned)(j*4+cc))*1024 + c]));
    out[((size_t)(b*1024 + c))*4 + q] = m;
}

// ---------------------------------------------------------------------------
__device__ __forceinline__ void bigrid(int k, int& lo, float& f) {
    float c = ((float)k + 0.5f) * (2.0f/7.0f) - 0.5f;
    c = fminf(fmaxf(c, 0.f), 1.f);
    float fl = floorf(c);
    lo = (int)fl;
    f = c - fl;
}

// bilinear+pad+im2col, x16 vectorized
__global__ void buildPb2(const float* __restrict__ pp, ushort* __restrict__ Pb) {
    int idx = blockIdx.x*256 + (int)threadIdx.x;   // 802,816 exactly
    int c = idx & 1023;
    int r = idx >> 10;
    int b = r & 15; int hw = r >> 4;
    int h = hw/7, w2 = hw%7;
    f32x4 qv = *(const f32x4*)(pp + ((size_t)(b*1024 + c))*4);
    float q0 = qv[0], q1 = qv[1], q2 = qv[2], q3 = qv[3];
    ushort u[16];
    UNR for (int k=0;k<9;++k) {
        int i = k/3, j = k%3;
        int rr = h + i - 1, cc = w2 + j - 1;
        float val = 0.f;
        if (rr>=0 && rr<7 && cc>=0 && cc<7) {
            int rlo; float rf; bigrid(rr, rlo, rf);
            int clo; float cf; bigrid(cc, clo, cf);
            float top0 = rlo ? q2 : q0, top1 = rlo ? q3 : q1;
            float v0 = clo ? top1 : top0;
            float v1 = top1;
            float bot0 = q2, bot1 = q3;
            float w0 = clo ? bot1 : bot0;
            float w1v = bot1;
            float top = v0*(1.f-cf) + v1*cf;
            float bot = w0*(1.f-cf) + w1v*cf;
            val = top*(1.f-rf) + bot*rf;
        }
        u[k] = f2bf(val);
    }
    UNR for (int k=9;k<16;++k) u[k] = 0;
    ushort* dst = Pb + (size_t)idx*16;
    *(short8v*)dst       = *(short8v*)&u[0];
    *(short8v*)(dst + 8) = *(short8v*)&u[8];
}

// ---------------------------------------------------------------------------
// Fused local-conv, barrier-free wave-partitioned staging; bf16 partials.
// ---------------------------------------------------------------------------
__global__ __launch_bounds__(256)
void lconv_fused(const float* __restrict__ lcw, const ushort* __restrict__ Pb,
                 ushort* __restrict__ part) {
    const int bid = (int)blockIdx.x;      // 0..783
    const int xcd = bid & 7;
    const int i   = bid >> 3;             // 0..97
    const int hw  = i % 49;
    const int ks  = xcd + 8*(i/49);       // 0..15, pinned to xcd
    const int t   = (int)threadIdx.x;
    const int lane = t & 63, w = t >> 6;
    const int lm = lane & 15, lk = lane >> 4;
    const int c0 = ks*64;

    __shared__ ushort A[2][8192];         // 2 x 16KB

    auto ldreg = [&](int cc, float (&w9)[2][9]) {
        const int cb = c0 + cc*2;
        UNR for (int cl=0; cl<2; ++cl) {
            const float* src = lcw + ((size_t)(cb+cl)*256 + (unsigned)(w*64+lane))*441
                             + hw*9;
            __builtin_memcpy(w9[cl], src, 36);
        }
    };
    auto wrlds = [&](int buf, float (&w9)[2][9]) {
        UNR for (int cl=0; cl<2; ++cl) {
            int rem = cl*256 + w*64 + lane;
            ushort u[16];
            UNR for (int k=0;k<8;++k) u[k]=f2bf(w9[cl][k]);
            u[8]=f2bf(w9[cl][8]);
            UNR for (int k=9;k<16;++k) u[k]=0;
            *(short8v*)&A[buf][(unsigned)rem*8u] = *(short8v*)&u[0];
            *(short8v*)&A[buf][4096u + (unsigned)rem*8u] = *(short8v*)&u[8];
        }
    };

    f32x4 acc[4];
    UNR for (int q=0;q<4;++q) acc[q] = f32x4{0.f,0.f,0.f,0.f};

    const ushort* Bb = Pb + (size_t)(hw*16 + lm)*16384 + ks*1024 + lk*8;
    const int arow = (lk&1)*512 + (lk>>1)*256 + w*64 + lm;

    auto mmac = [&](int buf, int cc) {
        short8v bv = *(const short8v*)(Bb + cc*32);
        UNR for (int mf = 0; mf < 4; ++mf) {
            short8v av = *(const short8v*)&A[buf][(unsigned)(arow + mf*16)*8u];
            acc[mf] = __builtin_amdgcn_mfma_f32_16x16x32_bf16(av, bv, acc[mf], 0,0,0);
        }
    };

    float wA[2][9], wB[2][9];
    ldreg(0, wA);
    wrlds(0, wA);
    ldreg(1, wB);
    for (int cc = 0; cc < 32; cc += 2) {
        mmac(0, cc);
        wrlds(1, wB);
        if (cc+2 < 32) ldreg(cc+2, wA);
        mmac(1, cc+1);
        if (cc+2 < 32) {
            wrlds(0, wA);
            if (cc+3 < 32) ldreg(cc+3, wB);
        }
    }

    UNR for (int mf=0; mf<4; ++mf)
        UNR for (int r=0;r<4;++r) {
            int o = w*64 + mf*16 + 4*lk + r;
            part[(((size_t)ks*49 + hw)*256 + o)*16 + lm] = f2bf(acc[mf][r]);
        }
}

// part [ks][hw][o][b] (bf16) -> yact[b][o*49+hw]; 4 b per thread (ushort4)
__global__ void lreduce2(const ushort* __restrict__ part, const float* __restrict__ lcb,
                         float* __restrict__ yact) {
    int idx = blockIdx.x*256 + (int)threadIdx.x;  // 50176 exactly
    int b4 = (idx & 3)*4; int o = (idx >> 2) & 255; int hw = idx >> 10;
    float sum[4] = {0.f, 0.f, 0.f, 0.f};
    UNR for (int ks=0; ks<16; ++ks) {
        ushort4 p = *(const ushort4*)(part + (((size_t)ks*49 + hw)*256 + o)*16 + b4);
        sum[0] += bf2f(p.x); sum[1] += bf2f(p.y);
        sum[2] += bf2f(p.z); sum[3] += bf2f(p.w);
    }
    float bias = lcb[o*49 + hw];
    UNR for (int r=0;r<4;++r) {
        float s = sum[r] + bias;
        yact[(b4+r)*12544 + o*49 + hw] = (s > 0.f) ? s : 0.1f*s;
    }
}

// ---------------------------------------------------------------------------
// FC: float4 weight stream (16B/lane), r19 version.
// ---------------------------------------------------------------------------
__global__ __launch_bounds__(256)
void fc_k(const float* __restrict__ act, const float* __restrict__ fw,
          const float* __restrict__ fb, float* __restrict__ out) {
    __shared__ float red[4][4][16];
    const int t = (int)threadIdx.x;
    const int o0 = blockIdx.x*4;
    float acc[4][16];
    UNR for (int oo=0;oo<4;++oo) UNR for (int b=0;b<16;++b) acc[oo][b]=0.f;

    const int kt = t*4;
    for (int k0 = 0; k0 < 12288; k0 += 1024) {
        int k = k0 + kt;
        f32x4 wv[4];
        UNR for (int oo=0;oo<4;++oo) {
            int o = o0+oo;
            wv[oo] = (o < 4949) ? *(const f32x4*)(fw + (size_t)o*12544 + k)
                                : f32x4{0.f,0.f,0.f,0.f};
        }
        UNR for (int b=0;b<16;++b) {
            f32x4 av = *(const f32x4*)(act + b*12544 + k);
            UNR for (int oo=0;oo<4;++oo) {
                acc[oo][b] = fmaf(wv[oo][0], av[0], acc[oo][b]);
                acc[oo][b] = fmaf(wv[oo][1], av[1], acc[oo][b]);
                acc[oo][b] = fmaf(wv[oo][2], av[2], acc[oo][b]);
                acc[oo][b] = fmaf(wv[oo][3], av[3], acc[oo][b]);
            }
        }
    }
    if (t < 64) {                       // tail k = 12288..12543
        int k = 12288 + kt;
        f32x4 wv[4];
        UNR for (int oo=0;oo<4;++oo) {
            int o = o0+oo;
            wv[oo] = (o < 4949) ? *(const f32x4*)(fw + (size_t)o*12544 + k)
                                : f32x4{0.f,0.f,0.f,0.f};
        }
        UNR for (int b=0;b<16;++b) {
            f32x4 av = *(const f32x4*)(act + b*12544 + k);
            UNR for (int oo=0;oo<4;++oo) {
                acc[oo][b] = fmaf(wv[oo][0], av[0], acc[oo][b]);
                acc[oo][b] = fmaf(wv[oo][1], av[1], acc[oo][b]);
                acc[oo][b] = fmaf(wv[oo][2], av[2], acc[oo][b]);
                acc[oo][b] = fmaf(wv[oo][3], av[3], acc[oo][b]);
            }
        }
    }

    UNR for (int oo=0;oo<4;++oo)
        UNR for (int b=0;b<16;++b) {
            float v = acc[oo][b];
            UNR for (int off=32; off; off>>=1) v += __shfl_xor(v, off, 64);
            acc[oo][b] = v;
        }
    const int wave = t>>6, lane = t&63;
    if (lane == 0)
        UNR for (int oo=0;oo<4;++oo)
            UNR for (int b=0;b<16;++b) red[wave][oo][b] = acc[oo][b];
    __syncthreads();
    if (t < 64) {
        int oo = t>>4, b = t&15;
        float v = red[0][oo][b]+red[1][oo][b]+red[2][oo][b]+red[3][oo][b];
        int o = o0+oo;
        if (o < 4949) out[b*4949 + o] = v + fb[o];
    }
}

// ---------------------------------------------------------------------------
extern "C" void kernel_launch(void* const* d_in, const int* in_sizes, int n_in,
                              void* d_out, int out_size, void* d_ws, size_t ws_size,
                              hipStream_t stream) {
    const float* x   = (const float*)d_in[0];
    const float* w1  = (const float*)d_in[1];
    const float* b1  = (const float*)d_in[2];
    const float* w3  = (const float*)d_in[3];
    const float* b3  = (const float*)d_in[4];
    const float* w4  = (const float*)d_in[5];
    const float* b4  = (const float*)d_in[6];
    const float* w7  = (const float*)d_in[7];
    const float* b7  = (const float*)d_in[8];
    const float* w8  = (const float*)d_in[9];
    const float* b8  = (const float*)d_in[10];
    const float* wu  = (const float*)d_in[11];
    const float* bu  = (const float*)d_in[12];
    const float* lcw = (const float*)d_in[13];
    const float* lcb = (const float*)d_in[14];
    const float* fw  = (const float*)d_in[15];
    const float* fb  = (const float*)d_in[16];
    float* out = (float*)d_out;

    // --- workspace carve (bytes, 256-aligned) ---
    char* base = (char*)d_ws;
    auto alloc = [&](size_t bytes) { char* p = base; base += (bytes + 255) & ~(size_t)255; return p; };
    ushort* X1  = (ushort*)alloc(16u*456*456*4*2);
    ushort* X3  = (ushort*)alloc(16u*114*114*64*2);
    ushort* X4  = (ushort*)alloc(16u*56*56*192*2);
    ushort* X7  = (ushort*)alloc(16u*27*27*256*2);   // later reused as yact
    ushort* X8  = (ushort*)alloc(16u*13*13*512*2);
    ushort* XU1 = (ushort*)alloc(16u*12*12*1024*2);
    ushort* XU2 = (ushort*)alloc(16u*11*11*1024*2);
    ushort* XU3 = (ushort*)alloc(16u*10*10*1024*2);
    ushort* W1b = (ushort*)alloc(64u*224*2);
    ushort* W3b = (ushort*)alloc(192u*576*2);
    ushort* W4b = (ushort*)alloc(256u*1728*2);
    ushort* W7b = (ushort*)alloc(512u*1024*2);
    ushort* W8b = (ushort*)alloc(1024u*2048*2);
    ushort* WUb = (ushort*)alloc(1024u*4096*2);
    float*  pp  = (float*)alloc(16u*1024*4*4);
    ushort* Pb  = (ushort*)alloc((size_t)49*16*16384*2);     // 25.7 MB
    ushort* part = (ushort*)alloc((size_t)16*49*256*16*2);   // 6.4 MB (bf16)
    ushort* partK = (ushort*)alloc((size_t)4*2304*1024*2);   // 18.9 MB (bf16)
    float*  yact = (float*)X7;                               // X7 dead by then

    // --- prep (ONE launch) ---
    megaprep<<<43644, 256, 0, stream>>>(x, X1, X3, w1, W1b, w3, W3b, w4, W4b,
                                        w7, W7b, w8, W8b, wu, WUb);

    // --- conv chain ---
    convc1<456,456,224,224,114,114,1,64, 4>
        <<<dim3(1,3136), 256, 0, stream>>>(X1, W1b, b1, X3);
    convt<64,3,1,114,114,112,112,192, true,56,56,0,192, 1,4,1, 3,784>
        <<<2352, 256, 0, stream>>>(X3, W3b, b3, X4, nullptr);
    convt<192,3,1,56,56,54,54,256, true,27,27,0,256, 2,2,1>
        <<<dim3(2,365,1), 256, 0, stream>>>(X4, W4b, b4, X7, nullptr);
    convt<256,2,1,27,27,26,26,512, true,13,13,0,512, 2,2,1>
        <<<dim3(4,85,1), 256, 0, stream>>>(X7, W7b, b7, X8, nullptr);
    convt<512,2,1,13,13,12,12,1024, false,12,12,0,1024, 2,2,4>
        <<<dim3(8,18,4), 256, 0, stream>>>(X8, W8b, nullptr, nullptr, partK);
    kreduce<1024,12,12,12,12,1024,4><<<2304, 256, 0, stream>>>(partK, b8, XU1);
    convt<1024,2,1,12,12,11,11,1024, false,11,11,0,1024, 2,2,4>
        <<<dim3(8,16,4), 256, 0, stream>>>(XU1, WUb, nullptr, nullptr, partK);
    kreduce<1024,11,11,11,11,1024,4><<<1936, 256, 0, stream>>>(partK, bu, XU2);
    convt<1024,2,1,11,11,10,10,1024, false,10,10,0,1024, 2,2,4>
        <<<dim3(8,13,4), 256, 0, stream>>>(XU2, WUb, nullptr, nullptr, partK);
    kreduce<1024,10,10,10,10,1024,4><<<1600, 256, 0, stream>>>(partK, bu, XU3);

    // --- head ---
    pool54_k<<<256, 256, 0, stream>>>(XU3, pp);
    buildPb2<<<3136, 256, 0, stream>>>(pp, Pb);
    lconv_fused<<<784, 256, 0, stream>>>(lcw, Pb, part);
    lreduce2<<<196, 256, 0, stream>>>(part, lcb, yact);
    fc_k<<<1238, 256, 0, stream>>>(yact, fw, fb, out);
}